// Round 6
// baseline (389.076 us; speedup 1.0000x reference)
//
#include <hip/hip_runtime.h>
#include <hip/hip_bf16.h>
#include <math.h>

#define B_SZ 2
#define T_LEN 1024
#define DMODEL 1024
#define DINNER 2048
#define DSTATE 16
#define DCONV 4
#define DTRANK 64
#define MTOK (B_SZ * T_LEN)   // 2048 tokens

// chunked scan
#define NC 8
#define CLEN (T_LEN / NC)               // 128
#define NSTATES (B_SZ * DINNER * DSTATE) // 65536

typedef __bf16 bf16x4 __attribute__((ext_vector_type(4)));
typedef __bf16 bf16x8 __attribute__((ext_vector_type(8)));
typedef float  f32x4  __attribute__((ext_vector_type(4)));

__device__ __forceinline__ float sigmoid_f(float v) { return 1.f / (1.f + __expf(-v)); }

// ---------------------------------------------------------------------------
// bf16 MFMA GEMM: C[M,N] = A[M,K] * B[N,K]^T, fp32 in/out, fp32 accumulate.
// 128x128 tile, 4 waves (2x2 of 64x64), K_STEP=64, v_mfma_f32_16x16x32_bf16.
// ---------------------------------------------------------------------------
#define LDK 72

__global__ __launch_bounds__(256) void mfma_gemm_nt(const float* __restrict__ A, int lda,
                                                    const float* __restrict__ Bm, int ldb,
                                                    float* __restrict__ C, int ldc,
                                                    int K)
{
    __shared__ __bf16 As[128 * LDK];
    __shared__ __bf16 Bs[128 * LDK];
    const int tid  = threadIdx.x;
    const int lane = tid & 63;
    const int w    = tid >> 6;
    const int wr   = w >> 1, wc = w & 1;
    const int m0   = blockIdx.y * 128, n0 = blockIdx.x * 128;

    const int srow  = tid >> 1;
    const int skoff = (tid & 1) * 32;

    f32x4 acc[4][4];
    #pragma unroll
    for (int i = 0; i < 4; ++i)
        #pragma unroll
        for (int j = 0; j < 4; ++j) {
            f32x4 z = {0.f, 0.f, 0.f, 0.f};
            acc[i][j] = z;
        }

    const int fr = lane & 15;
    const int kq = (lane >> 4) * 8;

    for (int k0 = 0; k0 < K; k0 += 64) {
        const float* gA = A  + (size_t)(m0 + srow) * lda + k0 + skoff;
        const float* gB = Bm + (size_t)(n0 + srow) * ldb + k0 + skoff;
        __bf16* sA = As + srow * LDK + skoff;
        __bf16* sB = Bs + srow * LDK + skoff;
        #pragma unroll
        for (int p = 0; p < 8; ++p) {
            float4 va = *reinterpret_cast<const float4*>(gA + 4 * p);
            bf16x4 ba = {(__bf16)va.x, (__bf16)va.y, (__bf16)va.z, (__bf16)va.w};
            *reinterpret_cast<bf16x4*>(sA + 4 * p) = ba;
            float4 vb = *reinterpret_cast<const float4*>(gB + 4 * p);
            bf16x4 bb = {(__bf16)vb.x, (__bf16)vb.y, (__bf16)vb.z, (__bf16)vb.w};
            *reinterpret_cast<bf16x4*>(sB + 4 * p) = bb;
        }
        __syncthreads();

        bf16x8 af[4][2], bfr[4][2];
        #pragma unroll
        for (int i = 0; i < 4; ++i) {
            const __bf16* pa = As + (wr * 64 + i * 16 + fr) * LDK + kq;
            af[i][0] = *reinterpret_cast<const bf16x8*>(pa);
            af[i][1] = *reinterpret_cast<const bf16x8*>(pa + 32);
        }
        #pragma unroll
        for (int j = 0; j < 4; ++j) {
            const __bf16* pb = Bs + (wc * 64 + j * 16 + fr) * LDK + kq;
            bfr[j][0] = *reinterpret_cast<const bf16x8*>(pb);
            bfr[j][1] = *reinterpret_cast<const bf16x8*>(pb + 32);
        }
        #pragma unroll
        for (int i = 0; i < 4; ++i)
            #pragma unroll
            for (int j = 0; j < 4; ++j) {
                acc[i][j] = __builtin_amdgcn_mfma_f32_16x16x32_bf16(af[i][0], bfr[j][0], acc[i][j], 0, 0, 0);
                acc[i][j] = __builtin_amdgcn_mfma_f32_16x16x32_bf16(af[i][1], bfr[j][1], acc[i][j], 0, 0, 0);
            }
        __syncthreads();
    }

    const int crow = (lane >> 4) * 4;
    const int ccol = lane & 15;
    #pragma unroll
    for (int i = 0; i < 4; ++i)
        #pragma unroll
        for (int j = 0; j < 4; ++j) {
            float* cp = C + (size_t)(m0 + wr * 64 + i * 16 + crow) * ldc
                          + n0 + wc * 64 + j * 16 + ccol;
            cp[0 * ldc] = acc[i][j][0];
            cp[1 * ldc] = acc[i][j][1];
            cp[2 * ldc] = acc[i][j][2];
            cp[3 * ldc] = acc[i][j][3];
        }
}

// ---------------------------------------------------------------------------
// fp32 vector GEMM (dt_proj): C[M,N] = A[M,K] * B[N,K]^T, EPI=softplus(+bias[m])
// ---------------------------------------------------------------------------
template<int EPI, int TA>
__global__ __launch_bounds__(256) void gemm_nt(const float* __restrict__ A, int lda,
                                               const float* __restrict__ Bm, int ldb,
                                               float* __restrict__ C, int ldc,
                                               int M, int N, int K,
                                               const float* __restrict__ bias)
{
    __shared__ float As[16][68];
    __shared__ float Bs[16][68];
    const int tx = threadIdx.x & 15;
    const int ty = threadIdx.x >> 4;
    const int m0 = blockIdx.y * 64;
    const int n0 = blockIdx.x * 64;
    const int lr = threadIdx.x >> 2;
    const int lc = (threadIdx.x & 3) * 4;
    const int kk16 = threadIdx.x >> 4;
    const int mc16 = (threadIdx.x & 15) * 4;

    float acc[4][4] = {};

    for (int k0 = 0; k0 < K; k0 += 16) {
        if (TA) {
            float4 v = *reinterpret_cast<const float4*>(&A[(size_t)(k0 + kk16) * lda + m0 + mc16]);
            As[kk16][mc16 + 0] = v.x; As[kk16][mc16 + 1] = v.y;
            As[kk16][mc16 + 2] = v.z; As[kk16][mc16 + 3] = v.w;
        } else {
            int m = m0 + lr;
            float4 v = make_float4(0.f, 0.f, 0.f, 0.f);
            if (m < M) v = *reinterpret_cast<const float4*>(&A[(size_t)m * lda + k0 + lc]);
            As[lc + 0][lr] = v.x; As[lc + 1][lr] = v.y;
            As[lc + 2][lr] = v.z; As[lc + 3][lr] = v.w;
        }
        {
            int n = n0 + lr;
            float4 v = make_float4(0.f, 0.f, 0.f, 0.f);
            if (n < N) v = *reinterpret_cast<const float4*>(&Bm[(size_t)n * ldb + k0 + lc]);
            Bs[lc + 0][lr] = v.x; Bs[lc + 1][lr] = v.y;
            Bs[lc + 2][lr] = v.z; Bs[lc + 3][lr] = v.w;
        }
        __syncthreads();
        #pragma unroll
        for (int kk = 0; kk < 16; ++kk) {
            float av[4], bv[4];
            #pragma unroll
            for (int i = 0; i < 4; ++i) av[i] = As[kk][ty + 16 * i];
            #pragma unroll
            for (int j = 0; j < 4; ++j) bv[j] = Bs[kk][tx + 16 * j];
            #pragma unroll
            for (int i = 0; i < 4; ++i)
                #pragma unroll
                for (int j = 0; j < 4; ++j)
                    acc[i][j] = fmaf(av[i], bv[j], acc[i][j]);
        }
        __syncthreads();
    }

    #pragma unroll
    for (int i = 0; i < 4; ++i) {
        int m = m0 + ty + 16 * i;
        if (m >= M) continue;
        float rb = (EPI == 2) ? bias[m] : 0.f;
        #pragma unroll
        for (int j = 0; j < 4; ++j) {
            int n = n0 + tx + 16 * j;
            if (n >= N) continue;
            float v = acc[i][j];
            if (EPI == 2) {
                v += rb;
                v = (v > 20.f) ? v : log1pf(__expf(v));
            }
            C[(size_t)m * ldc + n] = v;
        }
    }
}

// ---------------------------------------------------------------------------
// x_proj split-K
// ---------------------------------------------------------------------------
#define XP_KS 16
#define XP_KC (DINNER / XP_KS)   // 128

__global__ __launch_bounds__(256) void gemm_xproj_splitk(const float* __restrict__ xsT,
                                                         const float* __restrict__ W,
                                                         float* __restrict__ pbuf)
{
    __shared__ float As[16][68];
    __shared__ float Bs[16][68];
    const int tx = threadIdx.x & 15;
    const int ty = threadIdx.x >> 4;
    const int n0 = blockIdx.x * 64;
    const int m0 = blockIdx.y * 64;
    const int kz = blockIdx.z;
    const int lr = threadIdx.x >> 2;
    const int lc = (threadIdx.x & 3) * 4;
    const int kk16 = threadIdx.x >> 4;
    const int mc16 = (threadIdx.x & 15) * 4;

    float acc[4][4] = {};

    for (int k0 = kz * XP_KC; k0 < (kz + 1) * XP_KC; k0 += 16) {
        {
            float4 v = *reinterpret_cast<const float4*>(&xsT[(size_t)(k0 + kk16) * MTOK + m0 + mc16]);
            As[kk16][mc16 + 0] = v.x; As[kk16][mc16 + 1] = v.y;
            As[kk16][mc16 + 2] = v.z; As[kk16][mc16 + 3] = v.w;
        }
        {
            int n = n0 + lr;
            float4 v = make_float4(0.f, 0.f, 0.f, 0.f);
            if (n < DTRANK + 2 * DSTATE)
                v = *reinterpret_cast<const float4*>(&W[(size_t)n * DINNER + k0 + lc]);
            Bs[lc + 0][lr] = v.x; Bs[lc + 1][lr] = v.y;
            Bs[lc + 2][lr] = v.z; Bs[lc + 3][lr] = v.w;
        }
        __syncthreads();
        #pragma unroll
        for (int kk = 0; kk < 16; ++kk) {
            float av[4], bv[4];
            #pragma unroll
            for (int i = 0; i < 4; ++i) av[i] = As[kk][ty + 16 * i];
            #pragma unroll
            for (int j = 0; j < 4; ++j) bv[j] = Bs[kk][tx + 16 * j];
            #pragma unroll
            for (int i = 0; i < 4; ++i)
                #pragma unroll
                for (int j = 0; j < 4; ++j)
                    acc[i][j] = fmaf(av[i], bv[j], acc[i][j]);
        }
        __syncthreads();
    }

    float* pc = pbuf + (size_t)kz * MTOK * 96;
    #pragma unroll
    for (int i = 0; i < 4; ++i) {
        int m = m0 + ty + 16 * i;
        #pragma unroll
        for (int j = 0; j < 4; ++j) {
            int n = n0 + tx + 16 * j;
            if (n < 96) pc[(size_t)m * 96 + n] = acc[i][j];
        }
    }
}

__global__ __launch_bounds__(256) void reduce_xproj(const float* __restrict__ pbuf,
                                                    float* __restrict__ xdbl)
{
    const int idx = blockIdx.x * blockDim.x + threadIdx.x;
    const float4* p = reinterpret_cast<const float4*>(pbuf) + idx;
    float4 s = p[0];
    #pragma unroll
    for (int z = 1; z < XP_KS; ++z) {
        float4 v = p[(size_t)z * (MTOK * 96 / 4)];
        s.x += v.x; s.y += v.y; s.z += v.z; s.w += v.w;
    }
    reinterpret_cast<float4*>(xdbl)[idx] = s;
}

// causal depthwise conv (k=4, left pad 3) + bias + SiLU, output TRANSPOSED
__global__ __launch_bounds__(256) void conv_silu_t_kernel(const float* __restrict__ xz,
                                                          const float* __restrict__ cw,
                                                          const float* __restrict__ cb,
                                                          float* __restrict__ xsT)
{
    __shared__ float s_in[19][64];
    __shared__ float s_out[64][17];
    const int m0 = blockIdx.x * 16;
    const int d0 = blockIdx.y * 64;
    const int tid = threadIdx.x;
    const int tb = m0 & (T_LEN - 1);

    for (int idx = tid; idx < 19 * 64; idx += 256) {
        int r = idx >> 6, dd = idx & 63;
        float v = 0.f;
        if (tb + r - 3 >= 0)
            v = xz[(size_t)(m0 + r - 3) * (2 * DINNER) + d0 + dd];
        s_in[r][dd] = v;
    }
    __syncthreads();

    const int dl = tid & 63;
    const int tg = tid >> 6;
    const int d = d0 + dl;
    const float4 w = *reinterpret_cast<const float4*>(&cw[d * DCONV]);
    const float bia = cb[d];
    #pragma unroll
    for (int j = 0; j < 4; ++j) {
        int tt = tg * 4 + j;
        float acc = bia;
        acc = fmaf(s_in[tt + 0][dl], w.x, acc);
        acc = fmaf(s_in[tt + 1][dl], w.y, acc);
        acc = fmaf(s_in[tt + 2][dl], w.z, acc);
        acc = fmaf(s_in[tt + 3][dl], w.w, acc);
        s_out[dl][tt] = acc * sigmoid_f(acc);
    }
    __syncthreads();

    const int dd2 = tid >> 2;
    const int tc = (tid & 3) * 4;
    float4 o;
    o.x = s_out[dd2][tc + 0]; o.y = s_out[dd2][tc + 1];
    o.z = s_out[dd2][tc + 2]; o.w = s_out[dd2][tc + 3];
    *reinterpret_cast<float4*>(&xsT[(size_t)(d0 + dd2) * MTOK + m0 + tc]) = o;
}

// dst[r][c] = src[c][r]; grid = (C/32, R/32)  (used for bcT)
__global__ __launch_bounds__(256) void transpose32(const float* __restrict__ src, int ld_src,
                                                   float* __restrict__ dst, int ld_dst)
{
    __shared__ float t[32][33];
    const int c0 = blockIdx.x * 32;
    const int r0 = blockIdx.y * 32;
    const int tx = threadIdx.x & 31;
    const int ty = threadIdx.x >> 5;
    #pragma unroll
    for (int rep = 0; rep < 4; ++rep) {
        int row = ty + rep * 8;
        t[row][tx] = src[(size_t)(c0 + row) * ld_src + r0 + tx];
    }
    __syncthreads();
    #pragma unroll
    for (int rep = 0; rep < 4; ++rep) {
        int row = ty + rep * 8;
        dst[(size_t)(r0 + row) * ld_dst + c0 + tx] = t[tx][row];
    }
}

// yM[m][d] = yT[d][m] * silu(z[m][d]);  yT ld 4096 (in xz x-cols), z in xz z-cols
__global__ __launch_bounds__(256) void gate_transpose(const float* __restrict__ yT,
                                                      const float* __restrict__ xz,
                                                      float* __restrict__ yM)
{
    __shared__ float t[32][33];
    const int d0 = blockIdx.x * 32;
    const int m0 = blockIdx.y * 32;
    const int tx = threadIdx.x & 31;
    const int ty = threadIdx.x >> 5;
    #pragma unroll
    for (int rep = 0; rep < 4; ++rep) {
        int row = ty + rep * 8;
        t[row][tx] = yT[(size_t)(d0 + row) * 4096 + m0 + tx];
    }
    __syncthreads();
    #pragma unroll
    for (int rep = 0; rep < 4; ++rep) {
        int row = ty + rep * 8;
        int m = m0 + row;
        float zv = xz[(size_t)m * 4096 + 2048 + d0 + tx];
        float g = zv * sigmoid_f(zv);
        yM[(size_t)m * DINNER + d0 + tx] = t[tx][row] * g;
    }
}

// ---------------------------------------------------------------------------
// chunked selective scan: pass1 = chunk summaries (P = exp(a*sum dt), B = local
// scan from 0); pass2 = 8-step prefix over chunks (writes h_start in place of B);
// pass3 = local rescan with h_start, emitting y (+ xs*D), stored into yT.
// ---------------------------------------------------------------------------
__global__ __launch_bounds__(256) void scan_pass1(const float* __restrict__ dtT,
                                                  const float* __restrict__ xsT,
                                                  const float* __restrict__ bcT,
                                                  const float* __restrict__ A_log,
                                                  float* __restrict__ Pb,
                                                  float* __restrict__ Bb)
{
    const int wave = (blockIdx.x * blockDim.x + threadIdx.x) >> 6;   // 0..1023
    const int lane = threadIdx.x & 63;
    const int s = lane & 15;
    const int di = lane >> 4;
    const int c = blockIdx.y;
    const int b = wave >> 9;
    const int d = ((wave & 511) << 2) + di;

    const float a = -__expf(A_log[d * DSTATE + s]);

    const size_t toff = (size_t)b * T_LEN + (size_t)c * CLEN;
    const float4* dtp = reinterpret_cast<const float4*>(dtT + (size_t)d * MTOK + toff);
    const float4* xsp = reinterpret_cast<const float4*>(xsT + (size_t)d * MTOK + toff);
    const float4* Bp  = reinterpret_cast<const float4*>(bcT + (size_t)s * MTOK + toff);

    float4 dt0 = dtp[0], xs0 = xsp[0], B0 = Bp[0];
    float h = 0.f, sumdt = 0.f;

    for (int q = 0; q < CLEN / 4; ++q) {
        const float4 dtv = dt0, xv = xs0, Bv = B0;
        if (q < CLEN / 4 - 1) { dt0 = dtp[q + 1]; xs0 = xsp[q + 1]; B0 = Bp[q + 1]; }
        #define P1STEP(cc) {                                                    \
            const float dtj = dtv.cc; sumdt += dtj;                             \
            const float dA = __expf(dtj * a);                                   \
            h = fmaf(dA, h, dtj * xv.cc * Bv.cc); }
        P1STEP(x) P1STEP(y) P1STEP(z) P1STEP(w)
        #undef P1STEP
    }
    const size_t idx = (size_t)c * NSTATES + (size_t)(b * DINNER + d) * DSTATE + s;
    Pb[idx] = __expf(a * sumdt);
    Bb[idx] = h;
}

__global__ __launch_bounds__(256) void scan_pass2(const float* __restrict__ Pb,
                                                  float* __restrict__ Bb)
{
    const int idx = blockIdx.x * blockDim.x + threadIdx.x;  // 0..NSTATES-1
    float h = 0.f;
    #pragma unroll
    for (int c = 0; c < NC; ++c) {
        const size_t o = (size_t)c * NSTATES + idx;
        const float P  = Pb[o];
        const float Bv = Bb[o];
        Bb[o] = h;                 // h_start for chunk c
        h = fmaf(P, h, Bv);
    }
}

__global__ __launch_bounds__(256) void scan_pass3(const float* __restrict__ dtT,
                                                  const float* __restrict__ xsT,
                                                  const float* __restrict__ bcT,
                                                  const float* __restrict__ Hs,
                                                  const float* __restrict__ A_log,
                                                  const float* __restrict__ Dp,
                                                  float* __restrict__ yT)
{
    const int wave = (blockIdx.x * blockDim.x + threadIdx.x) >> 6;
    const int lane = threadIdx.x & 63;
    const int s = lane & 15;
    const int di = lane >> 4;
    const int c = blockIdx.y;
    const int b = wave >> 9;
    const int d = ((wave & 511) << 2) + di;

    const float a = -__expf(A_log[d * DSTATE + s]);
    const float Dv = Dp[d];

    const size_t toff = (size_t)b * T_LEN + (size_t)c * CLEN;
    const float4* dtp = reinterpret_cast<const float4*>(dtT + (size_t)d * MTOK + toff);
    const float4* xsp = reinterpret_cast<const float4*>(xsT + (size_t)d * MTOK + toff);
    const float4* Bp  = reinterpret_cast<const float4*>(bcT + (size_t)s * MTOK + toff);
    const float4* Cp  = reinterpret_cast<const float4*>(bcT + (size_t)(DSTATE + s) * MTOK + toff);
    float4* yp = reinterpret_cast<float4*>(yT + (size_t)d * 4096 + toff);

    float h = Hs[(size_t)c * NSTATES + (size_t)(b * DINNER + d) * DSTATE + s];

    float4 dt0 = dtp[0], xs0 = xsp[0], B0 = Bp[0], C0 = Cp[0];

    for (int q = 0; q < CLEN / 4; ++q) {
        const float4 dtv = dt0, xv = xs0, Bv = B0, Cv = C0;
        if (q < CLEN / 4 - 1) {
            dt0 = dtp[q + 1]; xs0 = xsp[q + 1]; B0 = Bp[q + 1]; C0 = Cp[q + 1];
        }
        float4 yv;
        #define SCAN_STEP(cc)                                                   \
        {                                                                       \
            const float dtj = dtv.cc;                                           \
            const float dA = __expf(dtj * a);                                   \
            h = fmaf(dA, h, dtj * xv.cc * Bv.cc);                               \
            float p = h * Cv.cc;                                                \
            p += __shfl_xor(p, 1, 64);                                          \
            p += __shfl_xor(p, 2, 64);                                          \
            p += __shfl_xor(p, 4, 64);                                          \
            p += __shfl_xor(p, 8, 64);                                          \
            yv.cc = p;                                                          \
        }
        SCAN_STEP(x) SCAN_STEP(y) SCAN_STEP(z) SCAN_STEP(w)
        #undef SCAN_STEP
        if (s == 0) {
            float4 o;
            o.x = yv.x + xv.x * Dv; o.y = yv.y + xv.y * Dv;
            o.z = yv.z + xv.z * Dv; o.w = yv.w + xv.w * Dv;
            yp[q] = o;
        }
    }
}

extern "C" void kernel_launch(void* const* d_in, const int* in_sizes, int n_in,
                              void* d_out, int out_size, void* d_ws, size_t ws_size,
                              hipStream_t stream) {
    const float* x         = (const float*)d_in[0];
    const float* in_proj_w = (const float*)d_in[1];
    const float* conv_w    = (const float*)d_in[2];
    const float* conv_b    = (const float*)d_in[3];
    const float* x_proj_w  = (const float*)d_in[4];
    const float* dt_proj_w = (const float*)d_in[5];
    const float* dt_proj_b = (const float*)d_in[6];
    const float* A_log     = (const float*)d_in[7];
    const float* D_param   = (const float*)d_in[8];
    const float* out_proj_w= (const float*)d_in[9];
    float* out = (float*)d_out;

    // ws (floats):
    // [0, 8M)        xz [2048][4096]; x-cols reused as yT after conv; z-cols live to gate
    // [8M, 12M)      xsT; reused as yM after scan
    // [12M, 16M)     pbuf (dead after reduce) then dtT
    // [16M, 16M+.25M)  xdbl + bcT
    // [+.25M, +1.25M)  Pb (0.5M), Bb (0.5M)
    float* ws   = (float*)d_ws;
    const size_t M4 = (size_t)4 * 1024 * 1024;
    float* xz   = ws;
    float* yT   = ws;            // x-cols of xz, ld 4096
    float* xsT  = ws + 2 * M4;
    float* yM   = ws + 2 * M4;
    float* pbuf = ws + 3 * M4;
    float* dtT  = ws + 3 * M4;
    float* xdbl = ws + 4 * M4;
    float* bcT  = xdbl + (size_t)MTOK * 96;
    float* Pb   = bcT + (size_t)2 * DSTATE * MTOK;
    float* Bb   = Pb + (size_t)NC * NSTATES;

    dim3 blk(256);

    // 1. in_proj (bf16 MFMA): xz[m][4096] = x @ in_proj_w^T
    mfma_gemm_nt<<<dim3((2 * DINNER) / 128, MTOK / 128), blk, 0, stream>>>(
        x, DMODEL, in_proj_w, DMODEL, xz, 2 * DINNER, DMODEL);

    // 2. causal conv + SiLU -> xsT[d][m]
    conv_silu_t_kernel<<<dim3(MTOK / 16, DINNER / 64), blk, 0, stream>>>(xz, conv_w, conv_b, xsT);

    // 3. x_proj split-K (fp32): pbuf[kz][m][96]
    gemm_xproj_splitk<<<dim3(2, MTOK / 64, XP_KS), blk, 0, stream>>>(xsT, x_proj_w, pbuf);

    // 4. reduce partials -> xdbl[m][96]
    reduce_xproj<<<dim3(MTOK * 96 / 4 / 256), blk, 0, stream>>>(pbuf, xdbl);

    // 5. dt_proj (fp32, transposed-out): dtT[e][m] = softplus(W_dt @ dt_in^T + b[e])
    gemm_nt<2, 0><<<dim3(32, 32), blk, 0, stream>>>(
        dt_proj_w, DTRANK, xdbl, 96, dtT, MTOK, DINNER, MTOK, DTRANK, dt_proj_b);

    // 6. bcT[0:16][m] = B^T, bcT[16:32][m] = C^T
    transpose32<<<dim3(MTOK / 32, 1), blk, 0, stream>>>(xdbl + DTRANK, 96, bcT, MTOK);

    // 7. chunked scan
    scan_pass1<<<dim3(256, NC), blk, 0, stream>>>(dtT, xsT, bcT, A_log, Pb, Bb);
    scan_pass2<<<dim3(NSTATES / 256), blk, 0, stream>>>(Pb, Bb);
    scan_pass3<<<dim3(256, NC), blk, 0, stream>>>(dtT, xsT, bcT, Bb, A_log, D_param, yT);

    // 8. gate + transpose: yM[m][d] = yT[d][m] * silu(z[m][d])
    gate_transpose<<<dim3(DINNER / 32, MTOK / 32), blk, 0, stream>>>(yT, xz, yM);

    // 9. out_proj (bf16 MFMA): out[m][1024] = y @ out_proj_w^T
    mfma_gemm_nt<<<dim3(DMODEL / 128, MTOK / 128), blk, 0, stream>>>(
        yM, DINNER, out_proj_w, DINNER, out, DMODEL, DINNER);
}

// Round 7
// 283.868 us; speedup vs baseline: 1.3706x; 1.3706x over previous
//
#include <hip/hip_runtime.h>
#include <hip/hip_bf16.h>
#include <math.h>

#define B_SZ 2
#define T_LEN 1024
#define DMODEL 1024
#define DINNER 2048
#define DSTATE 16
#define DCONV 4
#define DTRANK 64
#define MTOK (B_SZ * T_LEN)   // 2048 tokens

// chunked scan
#define NC 8
#define CLEN (T_LEN / NC)               // 128
#define NSTATES (B_SZ * DINNER * DSTATE) // 65536

typedef __bf16 bf16x4 __attribute__((ext_vector_type(4)));
typedef __bf16 bf16x8 __attribute__((ext_vector_type(8)));
typedef float  f32x4  __attribute__((ext_vector_type(4)));

__device__ __forceinline__ float sigmoid_f(float v) { return 1.f / (1.f + __expf(-v)); }

// ---------------------------------------------------------------------------
// fp32 -> bf16 elementwise convert (8 elements/thread)
// ---------------------------------------------------------------------------
__global__ __launch_bounds__(256) void convert_f32_bf16(const float* __restrict__ src,
                                                        __bf16* __restrict__ dst)
{
    const int i = blockIdx.x * blockDim.x + threadIdx.x;
    float4 a = reinterpret_cast<const float4*>(src)[2 * i];
    float4 b = reinterpret_cast<const float4*>(src)[2 * i + 1];
    bf16x8 o = {(__bf16)a.x, (__bf16)a.y, (__bf16)a.z, (__bf16)a.w,
                (__bf16)b.x, (__bf16)b.y, (__bf16)b.z, (__bf16)b.w};
    reinterpret_cast<bf16x8*>(dst)[i] = o;
}

// ---------------------------------------------------------------------------
// bf16 MFMA GEMM (m97 structure): C[M,N] = A[M,K] * B[N,K]^T, bf16 in, fp32 out.
// 128xBN tile, 4 waves (2x2), K_STEP=64, global_load_lds width-16 staging,
// linear LDS [rows][64] bf16, ds_read_b128 fragments.
// ---------------------------------------------------------------------------
template<int BN>
__global__ __launch_bounds__(256) void mfma_gemm_bf16(const __bf16* __restrict__ A, int lda,
                                                      const __bf16* __restrict__ Bm, int ldb,
                                                      float* __restrict__ C, int ldc, int K)
{
    constexpr int NF = BN / 32;          // col fragments per wave (4 or 2)
    constexpr int BCALLS = BN / 32;      // B staging calls
    __shared__ __align__(16) __bf16 As[128 * 64];
    __shared__ __align__(16) __bf16 Bs[BN * 64];
    const int tid  = threadIdx.x;
    const int lane = tid & 63;
    const int w    = tid >> 6;
    const int wr   = w >> 1, wc = w & 1;
    const int m0   = blockIdx.y * 128, n0 = blockIdx.x * BN;

    f32x4 acc[4][NF];
    #pragma unroll
    for (int i = 0; i < 4; ++i)
        #pragma unroll
        for (int j = 0; j < NF; ++j) {
            f32x4 z = {0.f, 0.f, 0.f, 0.f};
            acc[i][j] = z;
        }

    const int fr = lane & 15;
    const int kq = (lane >> 4) * 8;

    for (int k0 = 0; k0 < K; k0 += 64) {
        // stage A: 128x64 bf16 = 1024 16B-chunks; 4 calls x (4 waves x 64 lanes)
        #pragma unroll
        for (int c = 0; c < 4; ++c) {
            const int idx = c * 256 + tid;
            const int row = idx >> 3;
            const int kc  = (idx & 7) * 8;
            __builtin_amdgcn_global_load_lds(
                (const __attribute__((address_space(1))) unsigned int*)(A + (size_t)(m0 + row) * lda + k0 + kc),
                (__attribute__((address_space(3))) unsigned int*)(As + idx * 8),
                16, 0, 0);
        }
        // stage B: BNx64 bf16
        #pragma unroll
        for (int c = 0; c < BCALLS; ++c) {
            const int idx = c * 256 + tid;
            const int row = idx >> 3;
            const int kc  = (idx & 7) * 8;
            __builtin_amdgcn_global_load_lds(
                (const __attribute__((address_space(1))) unsigned int*)(Bm + (size_t)(n0 + row) * ldb + k0 + kc),
                (__attribute__((address_space(3))) unsigned int*)(Bs + idx * 8),
                16, 0, 0);
        }
        __syncthreads();   // compiler drains vmcnt before barrier

        bf16x8 af[4][2], bfr[NF][2];
        #pragma unroll
        for (int i = 0; i < 4; ++i) {
            const __bf16* pa = As + (wr * 64 + i * 16 + fr) * 64 + kq;
            af[i][0] = *reinterpret_cast<const bf16x8*>(pa);
            af[i][1] = *reinterpret_cast<const bf16x8*>(pa + 32);
        }
        #pragma unroll
        for (int j = 0; j < NF; ++j) {
            const __bf16* pb = Bs + (wc * (BN / 2) + j * 16 + fr) * 64 + kq;
            bfr[j][0] = *reinterpret_cast<const bf16x8*>(pb);
            bfr[j][1] = *reinterpret_cast<const bf16x8*>(pb + 32);
        }
        #pragma unroll
        for (int i = 0; i < 4; ++i)
            #pragma unroll
            for (int j = 0; j < NF; ++j) {
                acc[i][j] = __builtin_amdgcn_mfma_f32_16x16x32_bf16(af[i][0], bfr[j][0], acc[i][j], 0, 0, 0);
                acc[i][j] = __builtin_amdgcn_mfma_f32_16x16x32_bf16(af[i][1], bfr[j][1], acc[i][j], 0, 0, 0);
            }
        __syncthreads();
    }

    const int crow = (lane >> 4) * 4;
    const int ccol = lane & 15;
    #pragma unroll
    for (int i = 0; i < 4; ++i)
        #pragma unroll
        for (int j = 0; j < NF; ++j) {
            float* cp = C + (size_t)(m0 + wr * 64 + i * 16 + crow) * ldc
                          + n0 + wc * (BN / 2) + j * 16 + ccol;
            cp[0 * ldc] = acc[i][j][0];
            cp[1 * ldc] = acc[i][j][1];
            cp[2 * ldc] = acc[i][j][2];
            cp[3 * ldc] = acc[i][j][3];
        }
}

// ---------------------------------------------------------------------------
// fp32 vector GEMM (dt_proj): C[M,N] = A[M,K] * B[N,K]^T, EPI=softplus(+bias[m])
// ---------------------------------------------------------------------------
template<int EPI, int TA>
__global__ __launch_bounds__(256) void gemm_nt(const float* __restrict__ A, int lda,
                                               const float* __restrict__ Bm, int ldb,
                                               float* __restrict__ C, int ldc,
                                               int M, int N, int K,
                                               const float* __restrict__ bias)
{
    __shared__ float As[16][68];
    __shared__ float Bs[16][68];
    const int tx = threadIdx.x & 15;
    const int ty = threadIdx.x >> 4;
    const int m0 = blockIdx.y * 64;
    const int n0 = blockIdx.x * 64;
    const int lr = threadIdx.x >> 2;
    const int lc = (threadIdx.x & 3) * 4;
    const int kk16 = threadIdx.x >> 4;
    const int mc16 = (threadIdx.x & 15) * 4;

    float acc[4][4] = {};

    for (int k0 = 0; k0 < K; k0 += 16) {
        if (TA) {
            float4 v = *reinterpret_cast<const float4*>(&A[(size_t)(k0 + kk16) * lda + m0 + mc16]);
            As[kk16][mc16 + 0] = v.x; As[kk16][mc16 + 1] = v.y;
            As[kk16][mc16 + 2] = v.z; As[kk16][mc16 + 3] = v.w;
        } else {
            int m = m0 + lr;
            float4 v = make_float4(0.f, 0.f, 0.f, 0.f);
            if (m < M) v = *reinterpret_cast<const float4*>(&A[(size_t)m * lda + k0 + lc]);
            As[lc + 0][lr] = v.x; As[lc + 1][lr] = v.y;
            As[lc + 2][lr] = v.z; As[lc + 3][lr] = v.w;
        }
        {
            int n = n0 + lr;
            float4 v = make_float4(0.f, 0.f, 0.f, 0.f);
            if (n < N) v = *reinterpret_cast<const float4*>(&Bm[(size_t)n * ldb + k0 + lc]);
            Bs[lc + 0][lr] = v.x; Bs[lc + 1][lr] = v.y;
            Bs[lc + 2][lr] = v.z; Bs[lc + 3][lr] = v.w;
        }
        __syncthreads();
        #pragma unroll
        for (int kk = 0; kk < 16; ++kk) {
            float av[4], bv[4];
            #pragma unroll
            for (int i = 0; i < 4; ++i) av[i] = As[kk][ty + 16 * i];
            #pragma unroll
            for (int j = 0; j < 4; ++j) bv[j] = Bs[kk][tx + 16 * j];
            #pragma unroll
            for (int i = 0; i < 4; ++i)
                #pragma unroll
                for (int j = 0; j < 4; ++j)
                    acc[i][j] = fmaf(av[i], bv[j], acc[i][j]);
        }
        __syncthreads();
    }

    #pragma unroll
    for (int i = 0; i < 4; ++i) {
        int m = m0 + ty + 16 * i;
        if (m >= M) continue;
        float rb = (EPI == 2) ? bias[m] : 0.f;
        #pragma unroll
        for (int j = 0; j < 4; ++j) {
            int n = n0 + tx + 16 * j;
            if (n >= N) continue;
            float v = acc[i][j];
            if (EPI == 2) {
                v += rb;
                v = (v > 20.f) ? v : log1pf(__expf(v));
            }
            C[(size_t)m * ldc + n] = v;
        }
    }
}

// ---------------------------------------------------------------------------
// x_proj split-K
// ---------------------------------------------------------------------------
#define XP_KS 16
#define XP_KC (DINNER / XP_KS)   // 128

__global__ __launch_bounds__(256) void gemm_xproj_splitk(const float* __restrict__ xsT,
                                                         const float* __restrict__ W,
                                                         float* __restrict__ pbuf)
{
    __shared__ float As[16][68];
    __shared__ float Bs[16][68];
    const int tx = threadIdx.x & 15;
    const int ty = threadIdx.x >> 4;
    const int n0 = blockIdx.x * 64;
    const int m0 = blockIdx.y * 64;
    const int kz = blockIdx.z;
    const int lr = threadIdx.x >> 2;
    const int lc = (threadIdx.x & 3) * 4;
    const int kk16 = threadIdx.x >> 4;
    const int mc16 = (threadIdx.x & 15) * 4;

    float acc[4][4] = {};

    for (int k0 = kz * XP_KC; k0 < (kz + 1) * XP_KC; k0 += 16) {
        {
            float4 v = *reinterpret_cast<const float4*>(&xsT[(size_t)(k0 + kk16) * MTOK + m0 + mc16]);
            As[kk16][mc16 + 0] = v.x; As[kk16][mc16 + 1] = v.y;
            As[kk16][mc16 + 2] = v.z; As[kk16][mc16 + 3] = v.w;
        }
        {
            int n = n0 + lr;
            float4 v = make_float4(0.f, 0.f, 0.f, 0.f);
            if (n < DTRANK + 2 * DSTATE)
                v = *reinterpret_cast<const float4*>(&W[(size_t)n * DINNER + k0 + lc]);
            Bs[lc + 0][lr] = v.x; Bs[lc + 1][lr] = v.y;
            Bs[lc + 2][lr] = v.z; Bs[lc + 3][lr] = v.w;
        }
        __syncthreads();
        #pragma unroll
        for (int kk = 0; kk < 16; ++kk) {
            float av[4], bv[4];
            #pragma unroll
            for (int i = 0; i < 4; ++i) av[i] = As[kk][ty + 16 * i];
            #pragma unroll
            for (int j = 0; j < 4; ++j) bv[j] = Bs[kk][tx + 16 * j];
            #pragma unroll
            for (int i = 0; i < 4; ++i)
                #pragma unroll
                for (int j = 0; j < 4; ++j)
                    acc[i][j] = fmaf(av[i], bv[j], acc[i][j]);
        }
        __syncthreads();
    }

    float* pc = pbuf + (size_t)kz * MTOK * 96;
    #pragma unroll
    for (int i = 0; i < 4; ++i) {
        int m = m0 + ty + 16 * i;
        #pragma unroll
        for (int j = 0; j < 4; ++j) {
            int n = n0 + tx + 16 * j;
            if (n < 96) pc[(size_t)m * 96 + n] = acc[i][j];
        }
    }
}

__global__ __launch_bounds__(256) void reduce_xproj(const float* __restrict__ pbuf,
                                                    float* __restrict__ xdbl)
{
    const int idx = blockIdx.x * blockDim.x + threadIdx.x;
    const float4* p = reinterpret_cast<const float4*>(pbuf) + idx;
    float4 s = p[0];
    #pragma unroll
    for (int z = 1; z < XP_KS; ++z) {
        float4 v = p[(size_t)z * (MTOK * 96 / 4)];
        s.x += v.x; s.y += v.y; s.z += v.z; s.w += v.w;
    }
    reinterpret_cast<float4*>(xdbl)[idx] = s;
}

// causal depthwise conv (k=4, left pad 3) + bias + SiLU, output TRANSPOSED
__global__ __launch_bounds__(256) void conv_silu_t_kernel(const float* __restrict__ xz,
                                                          const float* __restrict__ cw,
                                                          const float* __restrict__ cb,
                                                          float* __restrict__ xsT)
{
    __shared__ float s_in[19][64];
    __shared__ float s_out[64][17];
    const int m0 = blockIdx.x * 16;
    const int d0 = blockIdx.y * 64;
    const int tid = threadIdx.x;
    const int tb = m0 & (T_LEN - 1);

    for (int idx = tid; idx < 19 * 64; idx += 256) {
        int r = idx >> 6, dd = idx & 63;
        float v = 0.f;
        if (tb + r - 3 >= 0)
            v = xz[(size_t)(m0 + r - 3) * (2 * DINNER) + d0 + dd];
        s_in[r][dd] = v;
    }
    __syncthreads();

    const int dl = tid & 63;
    const int tg = tid >> 6;
    const int d = d0 + dl;
    const float4 w = *reinterpret_cast<const float4*>(&cw[d * DCONV]);
    const float bia = cb[d];
    #pragma unroll
    for (int j = 0; j < 4; ++j) {
        int tt = tg * 4 + j;
        float acc = bia;
        acc = fmaf(s_in[tt + 0][dl], w.x, acc);
        acc = fmaf(s_in[tt + 1][dl], w.y, acc);
        acc = fmaf(s_in[tt + 2][dl], w.z, acc);
        acc = fmaf(s_in[tt + 3][dl], w.w, acc);
        s_out[dl][tt] = acc * sigmoid_f(acc);
    }
    __syncthreads();

    const int dd2 = tid >> 2;
    const int tc = (tid & 3) * 4;
    float4 o;
    o.x = s_out[dd2][tc + 0]; o.y = s_out[dd2][tc + 1];
    o.z = s_out[dd2][tc + 2]; o.w = s_out[dd2][tc + 3];
    *reinterpret_cast<float4*>(&xsT[(size_t)(d0 + dd2) * MTOK + m0 + tc]) = o;
}

// dst[r][c] = src[c][r]; grid = (C/32, R/32)  (used for bcT)
__global__ __launch_bounds__(256) void transpose32(const float* __restrict__ src, int ld_src,
                                                   float* __restrict__ dst, int ld_dst)
{
    __shared__ float t[32][33];
    const int c0 = blockIdx.x * 32;
    const int r0 = blockIdx.y * 32;
    const int tx = threadIdx.x & 31;
    const int ty = threadIdx.x >> 5;
    #pragma unroll
    for (int rep = 0; rep < 4; ++rep) {
        int row = ty + rep * 8;
        t[row][tx] = src[(size_t)(c0 + row) * ld_src + r0 + tx];
    }
    __syncthreads();
    #pragma unroll
    for (int rep = 0; rep < 4; ++rep) {
        int row = ty + rep * 8;
        dst[(size_t)(r0 + row) * ld_dst + c0 + tx] = t[tx][row];
    }
}

// yMb[m][d] = bf16( yT[d][m] * silu(z[m][d]) );  yT ld 4096 (xz x-cols)
__global__ __launch_bounds__(256) void gate_transpose(const float* __restrict__ yT,
                                                      const float* __restrict__ xz,
                                                      __bf16* __restrict__ yMb)
{
    __shared__ float t[32][33];
    const int d0 = blockIdx.x * 32;
    const int m0 = blockIdx.y * 32;
    const int tx = threadIdx.x & 31;
    const int ty = threadIdx.x >> 5;
    #pragma unroll
    for (int rep = 0; rep < 4; ++rep) {
        int row = ty + rep * 8;
        t[row][tx] = yT[(size_t)(d0 + row) * 4096 + m0 + tx];
    }
    __syncthreads();
    #pragma unroll
    for (int rep = 0; rep < 4; ++rep) {
        int row = ty + rep * 8;
        int m = m0 + row;
        float zv = xz[(size_t)m * 4096 + 2048 + d0 + tx];
        float g = zv * sigmoid_f(zv);
        yMb[(size_t)m * DINNER + d0 + tx] = (__bf16)(t[tx][row] * g);
    }
}

// ---------------------------------------------------------------------------
// chunked selective scan
// ---------------------------------------------------------------------------
__global__ __launch_bounds__(256) void scan_pass1(const float* __restrict__ dtT,
                                                  const float* __restrict__ xsT,
                                                  const float* __restrict__ bcT,
                                                  const float* __restrict__ A_log,
                                                  float* __restrict__ Pb,
                                                  float* __restrict__ Bb)
{
    const int wave = (blockIdx.x * blockDim.x + threadIdx.x) >> 6;   // 0..1023
    const int lane = threadIdx.x & 63;
    const int s = lane & 15;
    const int di = lane >> 4;
    const int c = blockIdx.y;
    const int b = wave >> 9;
    const int d = ((wave & 511) << 2) + di;

    const float a = -__expf(A_log[d * DSTATE + s]);

    const size_t toff = (size_t)b * T_LEN + (size_t)c * CLEN;
    const float4* dtp = reinterpret_cast<const float4*>(dtT + (size_t)d * MTOK + toff);
    const float4* xsp = reinterpret_cast<const float4*>(xsT + (size_t)d * MTOK + toff);
    const float4* Bp  = reinterpret_cast<const float4*>(bcT + (size_t)s * MTOK + toff);

    float4 dt0 = dtp[0], xs0 = xsp[0], B0 = Bp[0];
    float h = 0.f, sumdt = 0.f;

    for (int q = 0; q < CLEN / 4; ++q) {
        const float4 dtv = dt0, xv = xs0, Bv = B0;
        if (q < CLEN / 4 - 1) { dt0 = dtp[q + 1]; xs0 = xsp[q + 1]; B0 = Bp[q + 1]; }
        #define P1STEP(cc) {                                                    \
            const float dtj = dtv.cc; sumdt += dtj;                             \
            const float dA = __expf(dtj * a);                                   \
            h = fmaf(dA, h, dtj * xv.cc * Bv.cc); }
        P1STEP(x) P1STEP(y) P1STEP(z) P1STEP(w)
        #undef P1STEP
    }
    const size_t idx = (size_t)c * NSTATES + (size_t)(b * DINNER + d) * DSTATE + s;
    Pb[idx] = __expf(a * sumdt);
    Bb[idx] = h;
}

__global__ __launch_bounds__(256) void scan_pass2(const float* __restrict__ Pb,
                                                  float* __restrict__ Bb)
{
    const int idx = blockIdx.x * blockDim.x + threadIdx.x;  // 0..NSTATES-1
    float h = 0.f;
    #pragma unroll
    for (int c = 0; c < NC; ++c) {
        const size_t o = (size_t)c * NSTATES + idx;
        const float P  = Pb[o];
        const float Bv = Bb[o];
        Bb[o] = h;
        h = fmaf(P, h, Bv);
    }
}

__global__ __launch_bounds__(256) void scan_pass3(const float* __restrict__ dtT,
                                                  const float* __restrict__ xsT,
                                                  const float* __restrict__ bcT,
                                                  const float* __restrict__ Hs,
                                                  const float* __restrict__ A_log,
                                                  const float* __restrict__ Dp,
                                                  float* __restrict__ yT)
{
    const int wave = (blockIdx.x * blockDim.x + threadIdx.x) >> 6;
    const int lane = threadIdx.x & 63;
    const int s = lane & 15;
    const int di = lane >> 4;
    const int c = blockIdx.y;
    const int b = wave >> 9;
    const int d = ((wave & 511) << 2) + di;

    const float a = -__expf(A_log[d * DSTATE + s]);
    const float Dv = Dp[d];

    const size_t toff = (size_t)b * T_LEN + (size_t)c * CLEN;
    const float4* dtp = reinterpret_cast<const float4*>(dtT + (size_t)d * MTOK + toff);
    const float4* xsp = reinterpret_cast<const float4*>(xsT + (size_t)d * MTOK + toff);
    const float4* Bp  = reinterpret_cast<const float4*>(bcT + (size_t)s * MTOK + toff);
    const float4* Cp  = reinterpret_cast<const float4*>(bcT + (size_t)(DSTATE + s) * MTOK + toff);
    float4* yp = reinterpret_cast<float4*>(yT + (size_t)d * 4096 + toff);

    float h = Hs[(size_t)c * NSTATES + (size_t)(b * DINNER + d) * DSTATE + s];

    float4 dt0 = dtp[0], xs0 = xsp[0], B0 = Bp[0], C0 = Cp[0];

    for (int q = 0; q < CLEN / 4; ++q) {
        const float4 dtv = dt0, xv = xs0, Bv = B0, Cv = C0;
        if (q < CLEN / 4 - 1) {
            dt0 = dtp[q + 1]; xs0 = xsp[q + 1]; B0 = Bp[q + 1]; C0 = Cp[q + 1];
        }
        float4 yv;
        #define SCAN_STEP(cc)                                                   \
        {                                                                       \
            const float dtj = dtv.cc;                                           \
            const float dA = __expf(dtj * a);                                   \
            h = fmaf(dA, h, dtj * xv.cc * Bv.cc);                               \
            float p = h * Cv.cc;                                                \
            p += __shfl_xor(p, 1, 64);                                          \
            p += __shfl_xor(p, 2, 64);                                          \
            p += __shfl_xor(p, 4, 64);                                          \
            p += __shfl_xor(p, 8, 64);                                          \
            yv.cc = p;                                                          \
        }
        SCAN_STEP(x) SCAN_STEP(y) SCAN_STEP(z) SCAN_STEP(w)
        #undef SCAN_STEP
        if (s == 0) {
            float4 o;
            o.x = yv.x + xv.x * Dv; o.y = yv.y + xv.y * Dv;
            o.z = yv.z + xv.z * Dv; o.w = yv.w + xv.w * Dv;
            yp[q] = o;
        }
    }
}

extern "C" void kernel_launch(void* const* d_in, const int* in_sizes, int n_in,
                              void* d_out, int out_size, void* d_ws, size_t ws_size,
                              hipStream_t stream) {
    const float* x         = (const float*)d_in[0];
    const float* in_proj_w = (const float*)d_in[1];
    const float* conv_w    = (const float*)d_in[2];
    const float* conv_b    = (const float*)d_in[3];
    const float* x_proj_w  = (const float*)d_in[4];
    const float* dt_proj_w = (const float*)d_in[5];
    const float* dt_proj_b = (const float*)d_in[6];
    const float* A_log     = (const float*)d_in[7];
    const float* D_param   = (const float*)d_in[8];
    const float* out_proj_w= (const float*)d_in[9];
    float* out = (float*)d_out;

    // ws (floats):
    // [0, 8M)    xz [2048][4096]; x-cols->yT after conv; z-cols live to gate;
    //            whole region dead after gate -> wb_out bf16 at [0,1M)
    // [8M, 12M)  pre-in_proj: xb bf16 [8M,9M), wb_in bf16 [9M,11M);
    //            then xsT fp32 (step 2..pass3); then yMb bf16 [8M,10M)
    // [12M,16M)  pbuf (dead after reduce) then dtT
    // [16M, ..)  xdbl, bcT, Pb, Bb
    float* ws   = (float*)d_ws;
    const size_t M4 = (size_t)4 * 1024 * 1024;
    float*  xz     = ws;
    float*  yT     = ws;                            // ld 4096 (x-cols)
    __bf16* wb_out = (__bf16*)ws;
    float*  xsT    = ws + 2 * M4;
    __bf16* xb     = (__bf16*)(ws + 2 * M4);
    __bf16* wb_in  = (__bf16*)(ws + 2 * M4 + M4 / 4);
    __bf16* yMb    = (__bf16*)(ws + 2 * M4);
    float*  pbuf   = ws + 3 * M4;
    float*  dtT    = ws + 3 * M4;
    float*  xdbl   = ws + 4 * M4;
    float*  bcT    = xdbl + (size_t)MTOK * 96;
    float*  Pb     = bcT + (size_t)2 * DSTATE * MTOK;
    float*  Bb     = Pb + (size_t)NC * NSTATES;

    dim3 blk(256);

    // 0. bf16 conversions for in_proj operands
    convert_f32_bf16<<<dim3(MTOK * DMODEL / 8 / 256), blk, 0, stream>>>(x, xb);
    convert_f32_bf16<<<dim3(2 * DINNER * DMODEL / 8 / 256), blk, 0, stream>>>(in_proj_w, wb_in);

    // 1. in_proj (bf16 MFMA, global_load_lds): xz[m][4096]
    mfma_gemm_bf16<128><<<dim3((2 * DINNER) / 128, MTOK / 128), blk, 0, stream>>>(
        xb, DMODEL, wb_in, DMODEL, xz, 2 * DINNER, DMODEL);

    // 2. causal conv + SiLU -> xsT[d][m]
    conv_silu_t_kernel<<<dim3(MTOK / 16, DINNER / 64), blk, 0, stream>>>(xz, conv_w, conv_b, xsT);

    // 3. x_proj split-K (fp32): pbuf[kz][m][96]
    gemm_xproj_splitk<<<dim3(2, MTOK / 64, XP_KS), blk, 0, stream>>>(xsT, x_proj_w, pbuf);

    // 4. reduce partials -> xdbl[m][96]
    reduce_xproj<<<dim3(MTOK * 96 / 4 / 256), blk, 0, stream>>>(pbuf, xdbl);

    // 5. dt_proj (fp32, transposed-out): dtT[e][m] = softplus(W_dt @ dt_in^T + b[e])
    gemm_nt<2, 0><<<dim3(32, 32), blk, 0, stream>>>(
        dt_proj_w, DTRANK, xdbl, 96, dtT, MTOK, DINNER, MTOK, DTRANK, dt_proj_b);

    // 6. bcT[0:16][m] = B^T, bcT[16:32][m] = C^T
    transpose32<<<dim3(MTOK / 32, 1), blk, 0, stream>>>(xdbl + DTRANK, 96, bcT, MTOK);

    // 7. chunked scan
    scan_pass1<<<dim3(256, NC), blk, 0, stream>>>(dtT, xsT, bcT, A_log, Pb, Bb);
    scan_pass2<<<dim3(NSTATES / 256), blk, 0, stream>>>(Pb, Bb);
    scan_pass3<<<dim3(256, NC), blk, 0, stream>>>(dtT, xsT, bcT, Bb, A_log, D_param, yT);

    // 8. gate + transpose -> yMb bf16 [m][d]
    gate_transpose<<<dim3(DINNER / 32, MTOK / 32), blk, 0, stream>>>(yT, xz, yMb);

    // 8b. out_proj weight -> bf16 (xz region dead now)
    convert_f32_bf16<<<dim3(DMODEL * DINNER / 8 / 256), blk, 0, stream>>>(out_proj_w, wb_out);

    // 9. out_proj (bf16 MFMA): out[m][1024] = y @ out_proj_w^T
    mfma_gemm_bf16<64><<<dim3(DMODEL / 64, MTOK / 128), blk, 0, stream>>>(
        yMb, DINNER, wb_out, DINNER, out, DMODEL, DINNER);
}

// Round 8
// 202.915 us; speedup vs baseline: 1.9174x; 1.3989x over previous
//
#include <hip/hip_runtime.h>
#include <hip/hip_bf16.h>
#include <math.h>

#define B_SZ 2
#define T_LEN 1024
#define DMODEL 1024
#define DINNER 2048
#define DSTATE 16
#define DCONV 4
#define DTRANK 64
#define MTOK (B_SZ * T_LEN)   // 2048 tokens

// chunked scan: channel-per-thread, 16 states in registers
#define NC 32
#define CLEN (T_LEN / NC)                 // 32
#define NCH (B_SZ * DINNER)               // 4096 channels
#define NSTATES (NCH * DSTATE)            // 65536

typedef __bf16 bf16x4 __attribute__((ext_vector_type(4)));
typedef __bf16 bf16x8 __attribute__((ext_vector_type(8)));
typedef float  f32x4  __attribute__((ext_vector_type(4)));

__device__ __forceinline__ float sigmoid_f(float v) { return 1.f / (1.f + __expf(-v)); }

// ---------------------------------------------------------------------------
// fp32 -> bf16 elementwise convert (8 elements/thread)
// ---------------------------------------------------------------------------
__global__ __launch_bounds__(256) void convert_f32_bf16(const float* __restrict__ src,
                                                        __bf16* __restrict__ dst)
{
    const int i = blockIdx.x * blockDim.x + threadIdx.x;
    float4 a = reinterpret_cast<const float4*>(src)[2 * i];
    float4 b = reinterpret_cast<const float4*>(src)[2 * i + 1];
    bf16x8 o = {(__bf16)a.x, (__bf16)a.y, (__bf16)a.z, (__bf16)a.w,
                (__bf16)b.x, (__bf16)b.y, (__bf16)b.z, (__bf16)b.w};
    reinterpret_cast<bf16x8*>(dst)[i] = o;
}

// ---------------------------------------------------------------------------
// bf16 MFMA GEMM (m97 structure): C[M,N] = A[M,K] * B[N,K]^T, bf16 in, fp32 out.
// ---------------------------------------------------------------------------
template<int BN>
__global__ __launch_bounds__(256) void mfma_gemm_bf16(const __bf16* __restrict__ A, int lda,
                                                      const __bf16* __restrict__ Bm, int ldb,
                                                      float* __restrict__ C, int ldc, int K)
{
    constexpr int NF = BN / 32;
    constexpr int BCALLS = BN / 32;
    __shared__ __align__(16) __bf16 As[128 * 64];
    __shared__ __align__(16) __bf16 Bs[BN * 64];
    const int tid  = threadIdx.x;
    const int lane = tid & 63;
    const int w    = tid >> 6;
    const int wr   = w >> 1, wc = w & 1;
    const int m0   = blockIdx.y * 128, n0 = blockIdx.x * BN;

    f32x4 acc[4][NF];
    #pragma unroll
    for (int i = 0; i < 4; ++i)
        #pragma unroll
        for (int j = 0; j < NF; ++j) {
            f32x4 z = {0.f, 0.f, 0.f, 0.f};
            acc[i][j] = z;
        }

    const int fr = lane & 15;
    const int kq = (lane >> 4) * 8;

    for (int k0 = 0; k0 < K; k0 += 64) {
        #pragma unroll
        for (int c = 0; c < 4; ++c) {
            const int idx = c * 256 + tid;
            const int row = idx >> 3;
            const int kc  = (idx & 7) * 8;
            __builtin_amdgcn_global_load_lds(
                (const __attribute__((address_space(1))) unsigned int*)(A + (size_t)(m0 + row) * lda + k0 + kc),
                (__attribute__((address_space(3))) unsigned int*)(As + idx * 8),
                16, 0, 0);
        }
        #pragma unroll
        for (int c = 0; c < BCALLS; ++c) {
            const int idx = c * 256 + tid;
            const int row = idx >> 3;
            const int kc  = (idx & 7) * 8;
            __builtin_amdgcn_global_load_lds(
                (const __attribute__((address_space(1))) unsigned int*)(Bm + (size_t)(n0 + row) * ldb + k0 + kc),
                (__attribute__((address_space(3))) unsigned int*)(Bs + idx * 8),
                16, 0, 0);
        }
        __syncthreads();

        bf16x8 af[4][2], bfr[NF][2];
        #pragma unroll
        for (int i = 0; i < 4; ++i) {
            const __bf16* pa = As + (wr * 64 + i * 16 + fr) * 64 + kq;
            af[i][0] = *reinterpret_cast<const bf16x8*>(pa);
            af[i][1] = *reinterpret_cast<const bf16x8*>(pa + 32);
        }
        #pragma unroll
        for (int j = 0; j < NF; ++j) {
            const __bf16* pb = Bs + (wc * (BN / 2) + j * 16 + fr) * 64 + kq;
            bfr[j][0] = *reinterpret_cast<const bf16x8*>(pb);
            bfr[j][1] = *reinterpret_cast<const bf16x8*>(pb + 32);
        }
        #pragma unroll
        for (int i = 0; i < 4; ++i)
            #pragma unroll
            for (int j = 0; j < NF; ++j) {
                acc[i][j] = __builtin_amdgcn_mfma_f32_16x16x32_bf16(af[i][0], bfr[j][0], acc[i][j], 0, 0, 0);
                acc[i][j] = __builtin_amdgcn_mfma_f32_16x16x32_bf16(af[i][1], bfr[j][1], acc[i][j], 0, 0, 0);
            }
        __syncthreads();
    }

    const int crow = (lane >> 4) * 4;
    const int ccol = lane & 15;
    #pragma unroll
    for (int i = 0; i < 4; ++i)
        #pragma unroll
        for (int j = 0; j < NF; ++j) {
            float* cp = C + (size_t)(m0 + wr * 64 + i * 16 + crow) * ldc
                          + n0 + wc * (BN / 2) + j * 16 + ccol;
            cp[0 * ldc] = acc[i][j][0];
            cp[1 * ldc] = acc[i][j][1];
            cp[2 * ldc] = acc[i][j][2];
            cp[3 * ldc] = acc[i][j][3];
        }
}

// ---------------------------------------------------------------------------
// fp32 vector GEMM: C[M,N] = A[M,K] * B[N,K]^T.
// EPI: 0 = none, 1 = softplus(v + bias[col n])
// ---------------------------------------------------------------------------
template<int EPI>
__global__ __launch_bounds__(256) void gemm_nt(const float* __restrict__ A, int lda,
                                               const float* __restrict__ Bm, int ldb,
                                               float* __restrict__ C, int ldc,
                                               int M, int N, int K,
                                               const float* __restrict__ bias)
{
    __shared__ float As[16][68];
    __shared__ float Bs[16][68];
    const int tx = threadIdx.x & 15;
    const int ty = threadIdx.x >> 4;
    const int m0 = blockIdx.y * 64;
    const int n0 = blockIdx.x * 64;
    const int lr = threadIdx.x >> 2;
    const int lc = (threadIdx.x & 3) * 4;

    float acc[4][4] = {};

    for (int k0 = 0; k0 < K; k0 += 16) {
        {
            int m = m0 + lr;
            float4 v = make_float4(0.f, 0.f, 0.f, 0.f);
            if (m < M) v = *reinterpret_cast<const float4*>(&A[(size_t)m * lda + k0 + lc]);
            As[lc + 0][lr] = v.x; As[lc + 1][lr] = v.y;
            As[lc + 2][lr] = v.z; As[lc + 3][lr] = v.w;
        }
        {
            int n = n0 + lr;
            float4 v = make_float4(0.f, 0.f, 0.f, 0.f);
            if (n < N) v = *reinterpret_cast<const float4*>(&Bm[(size_t)n * ldb + k0 + lc]);
            Bs[lc + 0][lr] = v.x; Bs[lc + 1][lr] = v.y;
            Bs[lc + 2][lr] = v.z; Bs[lc + 3][lr] = v.w;
        }
        __syncthreads();
        #pragma unroll
        for (int kk = 0; kk < 16; ++kk) {
            float av[4], bv[4];
            #pragma unroll
            for (int i = 0; i < 4; ++i) av[i] = As[kk][ty + 16 * i];
            #pragma unroll
            for (int j = 0; j < 4; ++j) bv[j] = Bs[kk][tx + 16 * j];
            #pragma unroll
            for (int i = 0; i < 4; ++i)
                #pragma unroll
                for (int j = 0; j < 4; ++j)
                    acc[i][j] = fmaf(av[i], bv[j], acc[i][j]);
        }
        __syncthreads();
    }

    #pragma unroll
    for (int i = 0; i < 4; ++i) {
        int m = m0 + ty + 16 * i;
        if (m >= M) continue;
        #pragma unroll
        for (int j = 0; j < 4; ++j) {
            int n = n0 + tx + 16 * j;
            if (n >= N) continue;
            float v = acc[i][j];
            if (EPI == 1) {
                v += bias[n];
                v = (v > 20.f) ? v : log1pf(__expf(v));
            }
            C[(size_t)m * ldc + n] = v;
        }
    }
}

// ---------------------------------------------------------------------------
// x_proj split-K (A token-major xs[m][k])
// ---------------------------------------------------------------------------
#define XP_KS 16
#define XP_KC (DINNER / XP_KS)   // 128

__global__ __launch_bounds__(256) void gemm_xproj_splitk(const float* __restrict__ xs,
                                                         const float* __restrict__ W,
                                                         float* __restrict__ pbuf)
{
    __shared__ float As[16][68];
    __shared__ float Bs[16][68];
    const int tx = threadIdx.x & 15;
    const int ty = threadIdx.x >> 4;
    const int n0 = blockIdx.x * 64;
    const int m0 = blockIdx.y * 64;
    const int kz = blockIdx.z;
    const int lr = threadIdx.x >> 2;
    const int lc = (threadIdx.x & 3) * 4;

    float acc[4][4] = {};

    for (int k0 = kz * XP_KC; k0 < (kz + 1) * XP_KC; k0 += 16) {
        {
            float4 v = *reinterpret_cast<const float4*>(&xs[(size_t)(m0 + lr) * DINNER + k0 + lc]);
            As[lc + 0][lr] = v.x; As[lc + 1][lr] = v.y;
            As[lc + 2][lr] = v.z; As[lc + 3][lr] = v.w;
        }
        {
            int n = n0 + lr;
            float4 v = make_float4(0.f, 0.f, 0.f, 0.f);
            if (n < DTRANK + 2 * DSTATE)
                v = *reinterpret_cast<const float4*>(&W[(size_t)n * DINNER + k0 + lc]);
            Bs[lc + 0][lr] = v.x; Bs[lc + 1][lr] = v.y;
            Bs[lc + 2][lr] = v.z; Bs[lc + 3][lr] = v.w;
        }
        __syncthreads();
        #pragma unroll
        for (int kk = 0; kk < 16; ++kk) {
            float av[4], bv[4];
            #pragma unroll
            for (int i = 0; i < 4; ++i) av[i] = As[kk][ty + 16 * i];
            #pragma unroll
            for (int j = 0; j < 4; ++j) bv[j] = Bs[kk][tx + 16 * j];
            #pragma unroll
            for (int i = 0; i < 4; ++i)
                #pragma unroll
                for (int j = 0; j < 4; ++j)
                    acc[i][j] = fmaf(av[i], bv[j], acc[i][j]);
        }
        __syncthreads();
    }

    float* pc = pbuf + (size_t)kz * MTOK * 96;
    #pragma unroll
    for (int i = 0; i < 4; ++i) {
        int m = m0 + ty + 16 * i;
        #pragma unroll
        for (int j = 0; j < 4; ++j) {
            int n = n0 + tx + 16 * j;
            if (n < 96) pc[(size_t)m * 96 + n] = acc[i][j];
        }
    }
}

__global__ __launch_bounds__(256) void reduce_xproj(const float* __restrict__ pbuf,
                                                    float* __restrict__ xdbl)
{
    const int idx = blockIdx.x * blockDim.x + threadIdx.x;
    const float4* p = reinterpret_cast<const float4*>(pbuf) + idx;
    float4 s = p[0];
    #pragma unroll
    for (int z = 1; z < XP_KS; ++z) {
        float4 v = p[(size_t)z * (MTOK * 96 / 4)];
        s.x += v.x; s.y += v.y; s.z += v.z; s.w += v.w;
    }
    reinterpret_cast<float4*>(xdbl)[idx] = s;
}

// causal depthwise conv (k=4, left pad 3) + bias + SiLU, token-major output
__global__ __launch_bounds__(256) void conv_silu_kernel(const float* __restrict__ xz,
                                                        const float* __restrict__ cw,
                                                        const float* __restrict__ cb,
                                                        float* __restrict__ xs)
{
    int tid = blockIdx.x * blockDim.x + threadIdx.x;  // b*T*DINNER + t*DINNER + d
    int d = tid & (DINNER - 1);
    int t = (tid >> 11) & (T_LEN - 1);
    int b = tid >> 21;
    float acc = cb[d];
    const float4 w = *reinterpret_cast<const float4*>(&cw[d * DCONV]);
    float wv[4] = {w.x, w.y, w.z, w.w};
    #pragma unroll
    for (int j = 0; j < DCONV; ++j) {
        int tt = t - (DCONV - 1) + j;
        if (tt >= 0)
            acc = fmaf(xz[((size_t)(b * T_LEN + tt)) * (2 * DINNER) + d], wv[j], acc);
    }
    xs[tid] = acc * sigmoid_f(acc);
}

// ---------------------------------------------------------------------------
// chunked selective scan, channel-per-thread, 16 states in registers.
// pass1: chunk summaries (P = exp(a*sum dt), h-scan from 0)
// pass2: sequential prefix over NC chunks per state
// pass3: local rescan from h_start, fused +xs*D, gate silu(z), bf16 output.
// ---------------------------------------------------------------------------
__global__ __launch_bounds__(256) void scan_pass1(const float* __restrict__ dt,
                                                  const float* __restrict__ xs,
                                                  const float* __restrict__ xdbl,
                                                  const float* __restrict__ A_log,
                                                  float* __restrict__ Pb,
                                                  float* __restrict__ Bb)
{
    __shared__ float sB[CLEN][16];
    const int tid = threadIdx.x;
    const int g   = blockIdx.x * 256 + tid;     // global channel 0..4095
    const int c   = blockIdx.y;
    const int b   = g >> 11;
    const int d   = g & (DINNER - 1);
    const int m0  = b * T_LEN + c * CLEN;

    // stage B tile: CLEN x 16 floats
    if (tid < CLEN * 4) {
        int t = tid >> 2, s4 = (tid & 3) * 4;
        *reinterpret_cast<float4*>(&sB[t][s4]) =
            *reinterpret_cast<const float4*>(&xdbl[(size_t)(m0 + t) * 96 + DTRANK + s4]);
    }
    __syncthreads();

    float a[DSTATE], h[DSTATE];
    #pragma unroll
    for (int s4 = 0; s4 < DSTATE; s4 += 4) {
        float4 v = *reinterpret_cast<const float4*>(&A_log[d * DSTATE + s4]);
        a[s4 + 0] = -__expf(v.x); a[s4 + 1] = -__expf(v.y);
        a[s4 + 2] = -__expf(v.z); a[s4 + 3] = -__expf(v.w);
        h[s4 + 0] = 0.f; h[s4 + 1] = 0.f; h[s4 + 2] = 0.f; h[s4 + 3] = 0.f;
    }

    float sumdt = 0.f;
    float dtc = dt[(size_t)m0 * DINNER + d];
    float xc  = xs[(size_t)m0 * DINNER + d];
    for (int t = 0; t < CLEN; ++t) {
        float dtn = 0.f, xn = 0.f;
        if (t + 1 < CLEN) {
            dtn = dt[(size_t)(m0 + t + 1) * DINNER + d];
            xn  = xs[(size_t)(m0 + t + 1) * DINNER + d];
        }
        sumdt += dtc;
        const float u = dtc * xc;
        #pragma unroll
        for (int s = 0; s < DSTATE; ++s) {
            const float dA = __expf(dtc * a[s]);
            h[s] = fmaf(dA, h[s], u * sB[t][s]);
        }
        dtc = dtn; xc = xn;
    }

    float* pp = Pb + ((size_t)c * NCH + g) * DSTATE;
    float* bp = Bb + ((size_t)c * NCH + g) * DSTATE;
    #pragma unroll
    for (int s4 = 0; s4 < DSTATE; s4 += 4) {
        float4 pv = {__expf(a[s4] * sumdt), __expf(a[s4 + 1] * sumdt),
                     __expf(a[s4 + 2] * sumdt), __expf(a[s4 + 3] * sumdt)};
        *reinterpret_cast<float4*>(pp + s4) = pv;
        float4 hv = {h[s4], h[s4 + 1], h[s4 + 2], h[s4 + 3]};
        *reinterpret_cast<float4*>(bp + s4) = hv;
    }
}

__global__ __launch_bounds__(256) void scan_pass2(const float* __restrict__ Pb,
                                                  float* __restrict__ Bb)
{
    const int idx = blockIdx.x * blockDim.x + threadIdx.x;  // 0..NSTATES-1
    float h = 0.f;
    #pragma unroll
    for (int c = 0; c < NC; ++c) {
        const size_t o = (size_t)c * NSTATES + idx;
        const float P  = Pb[o];
        const float Bv = Bb[o];
        Bb[o] = h;
        h = fmaf(P, h, Bv);
    }
}

__global__ __launch_bounds__(256) void scan_pass3(const float* __restrict__ dt,
                                                  const float* __restrict__ xs,
                                                  const float* __restrict__ xdbl,
                                                  const float* __restrict__ Hs,
                                                  const float* __restrict__ A_log,
                                                  const float* __restrict__ Dp,
                                                  const float* __restrict__ xz,
                                                  __bf16* __restrict__ yMb)
{
    __shared__ float sBC[CLEN][32];   // cols 0..15 = B, 16..31 = C
    const int tid = threadIdx.x;
    const int g   = blockIdx.x * 256 + tid;
    const int c   = blockIdx.y;
    const int b   = g >> 11;
    const int d   = g & (DINNER - 1);
    const int m0  = b * T_LEN + c * CLEN;

    // stage B,C tile: CLEN x 32 floats
    {
        int t = tid >> 3, col = (tid & 7) * 4;
        if (t < CLEN)
            *reinterpret_cast<float4*>(&sBC[t][col]) =
                *reinterpret_cast<const float4*>(&xdbl[(size_t)(m0 + t) * 96 + DTRANK + col]);
    }
    __syncthreads();

    float a[DSTATE], h[DSTATE];
    #pragma unroll
    for (int s4 = 0; s4 < DSTATE; s4 += 4) {
        float4 v = *reinterpret_cast<const float4*>(&A_log[d * DSTATE + s4]);
        a[s4 + 0] = -__expf(v.x); a[s4 + 1] = -__expf(v.y);
        a[s4 + 2] = -__expf(v.z); a[s4 + 3] = -__expf(v.w);
        float4 hv = *reinterpret_cast<const float4*>(
            Hs + ((size_t)c * NCH + g) * DSTATE + s4);
        h[s4 + 0] = hv.x; h[s4 + 1] = hv.y; h[s4 + 2] = hv.z; h[s4 + 3] = hv.w;
    }
    const float Dv = Dp[d];

    float dtc = dt[(size_t)m0 * DINNER + d];
    float xc  = xs[(size_t)m0 * DINNER + d];
    float zc  = xz[(size_t)m0 * (2 * DINNER) + DINNER + d];
    for (int t = 0; t < CLEN; ++t) {
        float dtn = 0.f, xn = 0.f, zn = 0.f;
        if (t + 1 < CLEN) {
            dtn = dt[(size_t)(m0 + t + 1) * DINNER + d];
            xn  = xs[(size_t)(m0 + t + 1) * DINNER + d];
            zn  = xz[(size_t)(m0 + t + 1) * (2 * DINNER) + DINNER + d];
        }
        const float u = dtc * xc;
        float y0 = 0.f, y1 = 0.f, y2 = 0.f, y3 = 0.f;
        #pragma unroll
        for (int s = 0; s < DSTATE; s += 4) {
            float dA0 = __expf(dtc * a[s + 0]);
            float dA1 = __expf(dtc * a[s + 1]);
            float dA2 = __expf(dtc * a[s + 2]);
            float dA3 = __expf(dtc * a[s + 3]);
            h[s + 0] = fmaf(dA0, h[s + 0], u * sBC[t][s + 0]);
            h[s + 1] = fmaf(dA1, h[s + 1], u * sBC[t][s + 1]);
            h[s + 2] = fmaf(dA2, h[s + 2], u * sBC[t][s + 2]);
            h[s + 3] = fmaf(dA3, h[s + 3], u * sBC[t][s + 3]);
            y0 = fmaf(h[s + 0], sBC[t][16 + s + 0], y0);
            y1 = fmaf(h[s + 1], sBC[t][16 + s + 1], y1);
            y2 = fmaf(h[s + 2], sBC[t][16 + s + 2], y2);
            y3 = fmaf(h[s + 3], sBC[t][16 + s + 3], y3);
        }
        float y = (y0 + y1) + (y2 + y3) + xc * Dv;
        const float gate = zc * sigmoid_f(zc);
        yMb[(size_t)(m0 + t) * DINNER + d] = (__bf16)(y * gate);
        dtc = dtn; xc = xn; zc = zn;
    }
}

extern "C" void kernel_launch(void* const* d_in, const int* in_sizes, int n_in,
                              void* d_out, int out_size, void* d_ws, size_t ws_size,
                              hipStream_t stream) {
    const float* x         = (const float*)d_in[0];
    const float* in_proj_w = (const float*)d_in[1];
    const float* conv_w    = (const float*)d_in[2];
    const float* conv_b    = (const float*)d_in[3];
    const float* x_proj_w  = (const float*)d_in[4];
    const float* dt_proj_w = (const float*)d_in[5];
    const float* dt_proj_b = (const float*)d_in[6];
    const float* A_log     = (const float*)d_in[7];
    const float* D_param   = (const float*)d_in[8];
    const float* out_proj_w= (const float*)d_in[9];
    float* out = (float*)d_out;

    // ws (floats):
    // [0, 8M)      xz [2048][4096]; z-cols live until pass3
    // [8M, 12M)    pre-in_proj: xb bf16 [8M,9M), wb_in bf16 [9M,11M); then xs fp32
    // [12M, 16M)   dt fp32; after pass3: wb_out bf16 at [12M,13M)
    // [16M, 20M)   pbuf (dead after reduce); then Pb [16M,18M), Bb [18M,20M);
    //              yMb bf16 [16M,17M) overlapping Pb (dead after pass2)
    // [20M, 20.25M) xdbl
    float* ws   = (float*)d_ws;
    const size_t M1 = (size_t)1024 * 1024;
    float*  xz     = ws;
    float*  xs     = ws + 8 * M1;
    __bf16* xb     = (__bf16*)(ws + 8 * M1);
    __bf16* wb_in  = (__bf16*)(ws + 9 * M1);
    float*  dt     = ws + 12 * M1;
    __bf16* wb_out = (__bf16*)(ws + 12 * M1);
    float*  pbuf   = ws + 16 * M1;
    float*  Pb     = ws + 16 * M1;
    float*  Bb     = ws + 18 * M1;
    __bf16* yMb    = (__bf16*)(ws + 16 * M1);
    float*  xdbl   = ws + 20 * M1;

    dim3 blk(256);

    // 0. bf16 conversions for in_proj operands
    convert_f32_bf16<<<dim3(MTOK * DMODEL / 8 / 256), blk, 0, stream>>>(x, xb);
    convert_f32_bf16<<<dim3(2 * DINNER * DMODEL / 8 / 256), blk, 0, stream>>>(in_proj_w, wb_in);

    // 1. in_proj (bf16 MFMA): xz[m][4096]
    mfma_gemm_bf16<128><<<dim3((2 * DINNER) / 128, MTOK / 128), blk, 0, stream>>>(
        xb, DMODEL, wb_in, DMODEL, xz, 2 * DINNER, DMODEL);

    // 2. causal conv + SiLU -> xs[m][d] (token-major)
    conv_silu_kernel<<<dim3(B_SZ * T_LEN * DINNER / 256), blk, 0, stream>>>(xz, conv_w, conv_b, xs);

    // 3. x_proj split-K: pbuf[kz][m][96]
    gemm_xproj_splitk<<<dim3(2, MTOK / 64, XP_KS), blk, 0, stream>>>(xs, x_proj_w, pbuf);

    // 4. reduce partials -> xdbl[m][96]
    reduce_xproj<<<dim3(MTOK * 96 / 4 / 256), blk, 0, stream>>>(pbuf, xdbl);

    // 5. dt_proj (fp32, token-major out): dt[m][i] = softplus(xdbl[:, :64] @ W^T + b[i])
    gemm_nt<1><<<dim3(DINNER / 64, MTOK / 64), blk, 0, stream>>>(
        xdbl, 96, dt_proj_w, DTRANK, dt, DINNER, MTOK, DINNER, DTRANK, dt_proj_b);

    // 6. chunked scan (fused gate+D epilogue in pass3) -> yMb bf16 [m][d]
    scan_pass1<<<dim3(NCH / 256, NC), blk, 0, stream>>>(dt, xs, xdbl, A_log, Pb, Bb);
    scan_pass2<<<dim3(NSTATES / 256), blk, 0, stream>>>(Pb, Bb);
    scan_pass3<<<dim3(NCH / 256, NC), blk, 0, stream>>>(dt, xs, xdbl, Bb, A_log, D_param, xz, yMb);

    // 7. out_proj weight -> bf16 (dt region dead after pass3)
    convert_f32_bf16<<<dim3(DMODEL * DINNER / 8 / 256), blk, 0, stream>>>(out_proj_w, wb_out);

    // 8. out_proj (bf16 MFMA): out[m][1024] = y @ out_proj_w^T
    mfma_gemm_bf16<64><<<dim3(DMODEL / 64, MTOK / 128), blk, 0, stream>>>(
        yMb, DINNER, wb_out, DINNER, out, DMODEL, DINNER);
}

// Round 9
// 194.156 us; speedup vs baseline: 2.0039x; 1.0451x over previous
//
#include <hip/hip_runtime.h>
#include <hip/hip_bf16.h>
#include <math.h>

#define B_SZ 2
#define T_LEN 1024
#define DMODEL 1024
#define DINNER 2048
#define DSTATE 16
#define DCONV 4
#define DTRANK 64
#define MTOK (B_SZ * T_LEN)   // 2048 tokens

// chunked scan: channel-per-thread, 16 states in registers
#define NC 32
#define CLEN (T_LEN / NC)                 // 32
#define NCH (B_SZ * DINNER)               // 4096 channels
#define NSTATES (NCH * DSTATE)            // 65536

typedef __bf16 bf16x4 __attribute__((ext_vector_type(4)));
typedef __bf16 bf16x8 __attribute__((ext_vector_type(8)));
typedef float  f32x4  __attribute__((ext_vector_type(4)));

__device__ __forceinline__ float sigmoid_f(float v) { return 1.f / (1.f + __expf(-v)); }

// ---------------------------------------------------------------------------
// one-shot bf16 conversion of x, in_proj_w, out_proj_w (8 elems/thread)
// segments (in 8-elem groups): x = 262144, in_w = 524288, out_w = 262144
// ---------------------------------------------------------------------------
__global__ __launch_bounds__(256) void convert3(const float* __restrict__ x,
                                                const float* __restrict__ w_in,
                                                const float* __restrict__ w_out,
                                                __bf16* __restrict__ xb,
                                                __bf16* __restrict__ wb_in,
                                                __bf16* __restrict__ wb_out)
{
    const int gi = blockIdx.x * blockDim.x + threadIdx.x;
    const float* src; __bf16* dst; int o;
    if (gi < 262144)            { src = x;     dst = xb;     o = gi; }
    else if (gi < 786432)       { src = w_in;  dst = wb_in;  o = gi - 262144; }
    else                        { src = w_out; dst = wb_out; o = gi - 786432; }
    float4 a = reinterpret_cast<const float4*>(src)[2 * o];
    float4 b = reinterpret_cast<const float4*>(src)[2 * o + 1];
    bf16x8 v = {(__bf16)a.x, (__bf16)a.y, (__bf16)a.z, (__bf16)a.w,
                (__bf16)b.x, (__bf16)b.y, (__bf16)b.z, (__bf16)b.w};
    reinterpret_cast<bf16x8*>(dst)[o] = v;
}

// ---------------------------------------------------------------------------
// bf16 MFMA GEMM (m97 structure): C[M,N] = A[M,K] * B[N,K]^T, bf16 in, CT out.
// ---------------------------------------------------------------------------
template<int BN, typename CT>
__global__ __launch_bounds__(256) void mfma_gemm_bf16(const __bf16* __restrict__ A, int lda,
                                                      const __bf16* __restrict__ Bm, int ldb,
                                                      CT* __restrict__ C, int ldc, int K)
{
    constexpr int NF = BN / 32;
    constexpr int BCALLS = BN / 32;
    __shared__ __align__(16) __bf16 As[128 * 64];
    __shared__ __align__(16) __bf16 Bs[BN * 64];
    const int tid  = threadIdx.x;
    const int lane = tid & 63;
    const int w    = tid >> 6;
    const int wr   = w >> 1, wc = w & 1;
    const int m0   = blockIdx.y * 128, n0 = blockIdx.x * BN;

    f32x4 acc[4][NF];
    #pragma unroll
    for (int i = 0; i < 4; ++i)
        #pragma unroll
        for (int j = 0; j < NF; ++j) {
            f32x4 z = {0.f, 0.f, 0.f, 0.f};
            acc[i][j] = z;
        }

    const int fr = lane & 15;
    const int kq = (lane >> 4) * 8;

    for (int k0 = 0; k0 < K; k0 += 64) {
        #pragma unroll
        for (int c = 0; c < 4; ++c) {
            const int idx = c * 256 + tid;
            const int row = idx >> 3;
            const int kc  = (idx & 7) * 8;
            __builtin_amdgcn_global_load_lds(
                (const __attribute__((address_space(1))) unsigned int*)(A + (size_t)(m0 + row) * lda + k0 + kc),
                (__attribute__((address_space(3))) unsigned int*)(As + idx * 8),
                16, 0, 0);
        }
        #pragma unroll
        for (int c = 0; c < BCALLS; ++c) {
            const int idx = c * 256 + tid;
            const int row = idx >> 3;
            const int kc  = (idx & 7) * 8;
            __builtin_amdgcn_global_load_lds(
                (const __attribute__((address_space(1))) unsigned int*)(Bm + (size_t)(n0 + row) * ldb + k0 + kc),
                (__attribute__((address_space(3))) unsigned int*)(Bs + idx * 8),
                16, 0, 0);
        }
        __syncthreads();

        bf16x8 af[4][2], bfr[NF][2];
        #pragma unroll
        for (int i = 0; i < 4; ++i) {
            const __bf16* pa = As + (wr * 64 + i * 16 + fr) * 64 + kq;
            af[i][0] = *reinterpret_cast<const bf16x8*>(pa);
            af[i][1] = *reinterpret_cast<const bf16x8*>(pa + 32);
        }
        #pragma unroll
        for (int j = 0; j < NF; ++j) {
            const __bf16* pb = Bs + (wc * (BN / 2) + j * 16 + fr) * 64 + kq;
            bfr[j][0] = *reinterpret_cast<const bf16x8*>(pb);
            bfr[j][1] = *reinterpret_cast<const bf16x8*>(pb + 32);
        }
        #pragma unroll
        for (int i = 0; i < 4; ++i)
            #pragma unroll
            for (int j = 0; j < NF; ++j) {
                acc[i][j] = __builtin_amdgcn_mfma_f32_16x16x32_bf16(af[i][0], bfr[j][0], acc[i][j], 0, 0, 0);
                acc[i][j] = __builtin_amdgcn_mfma_f32_16x16x32_bf16(af[i][1], bfr[j][1], acc[i][j], 0, 0, 0);
            }
        __syncthreads();
    }

    const int crow = (lane >> 4) * 4;
    const int ccol = lane & 15;
    #pragma unroll
    for (int i = 0; i < 4; ++i)
        #pragma unroll
        for (int j = 0; j < NF; ++j) {
            CT* cp = C + (size_t)(m0 + wr * 64 + i * 16 + crow) * ldc
                       + n0 + wc * (BN / 2) + j * 16 + ccol;
            cp[0 * (size_t)ldc] = (CT)acc[i][j][0];
            cp[1 * (size_t)ldc] = (CT)acc[i][j][1];
            cp[2 * (size_t)ldc] = (CT)acc[i][j][2];
            cp[3 * (size_t)ldc] = (CT)acc[i][j][3];
        }
}

// ---------------------------------------------------------------------------
// dt_proj fp32 GEMM: dt[m][n] = softplus(xdbl[m][0:64] . W[n][0:64] + bias[n]),
// output bf16. M=N=2048, K=64.
// ---------------------------------------------------------------------------
__global__ __launch_bounds__(256) void gemm_dtproj(const float* __restrict__ A,      // xdbl, lda 96
                                                   const float* __restrict__ Bm,     // dt_proj_w, ldb 64
                                                   __bf16* __restrict__ C,           // dt, ldc DINNER
                                                   const float* __restrict__ bias)
{
    __shared__ float As[16][68];
    __shared__ float Bs[16][68];
    const int tx = threadIdx.x & 15;
    const int ty = threadIdx.x >> 4;
    const int m0 = blockIdx.y * 64;
    const int n0 = blockIdx.x * 64;
    const int lr = threadIdx.x >> 2;
    const int lc = (threadIdx.x & 3) * 4;

    float acc[4][4] = {};

    for (int k0 = 0; k0 < DTRANK; k0 += 16) {
        {
            float4 v = *reinterpret_cast<const float4*>(&A[(size_t)(m0 + lr) * 96 + k0 + lc]);
            As[lc + 0][lr] = v.x; As[lc + 1][lr] = v.y;
            As[lc + 2][lr] = v.z; As[lc + 3][lr] = v.w;
        }
        {
            float4 v = *reinterpret_cast<const float4*>(&Bm[(size_t)(n0 + lr) * DTRANK + k0 + lc]);
            Bs[lc + 0][lr] = v.x; Bs[lc + 1][lr] = v.y;
            Bs[lc + 2][lr] = v.z; Bs[lc + 3][lr] = v.w;
        }
        __syncthreads();
        #pragma unroll
        for (int kk = 0; kk < 16; ++kk) {
            float av[4], bv[4];
            #pragma unroll
            for (int i = 0; i < 4; ++i) av[i] = As[kk][ty + 16 * i];
            #pragma unroll
            for (int j = 0; j < 4; ++j) bv[j] = Bs[kk][tx + 16 * j];
            #pragma unroll
            for (int i = 0; i < 4; ++i)
                #pragma unroll
                for (int j = 0; j < 4; ++j)
                    acc[i][j] = fmaf(av[i], bv[j], acc[i][j]);
        }
        __syncthreads();
    }

    #pragma unroll
    for (int i = 0; i < 4; ++i) {
        int m = m0 + ty + 16 * i;
        #pragma unroll
        for (int j = 0; j < 4; ++j) {
            int n = n0 + tx + 16 * j;
            float v = acc[i][j] + bias[n];
            v = (v > 20.f) ? v : log1pf(__expf(v));
            C[(size_t)m * DINNER + n] = (__bf16)v;
        }
    }
}

// ---------------------------------------------------------------------------
// x_proj split-K (A = xs bf16 token-major)
// ---------------------------------------------------------------------------
#define XP_KS 16
#define XP_KC (DINNER / XP_KS)   // 128

__global__ __launch_bounds__(256) void gemm_xproj_splitk(const __bf16* __restrict__ xsb,
                                                         const float* __restrict__ W,
                                                         float* __restrict__ pbuf)
{
    __shared__ float As[16][68];
    __shared__ float Bs[16][68];
    const int tx = threadIdx.x & 15;
    const int ty = threadIdx.x >> 4;
    const int n0 = blockIdx.x * 64;
    const int m0 = blockIdx.y * 64;
    const int kz = blockIdx.z;
    const int lr = threadIdx.x >> 2;
    const int lc = (threadIdx.x & 3) * 4;

    float acc[4][4] = {};

    for (int k0 = kz * XP_KC; k0 < (kz + 1) * XP_KC; k0 += 16) {
        {
            bf16x4 v = *reinterpret_cast<const bf16x4*>(&xsb[(size_t)(m0 + lr) * DINNER + k0 + lc]);
            As[lc + 0][lr] = (float)v[0]; As[lc + 1][lr] = (float)v[1];
            As[lc + 2][lr] = (float)v[2]; As[lc + 3][lr] = (float)v[3];
        }
        {
            int n = n0 + lr;
            float4 v = make_float4(0.f, 0.f, 0.f, 0.f);
            if (n < DTRANK + 2 * DSTATE)
                v = *reinterpret_cast<const float4*>(&W[(size_t)n * DINNER + k0 + lc]);
            Bs[lc + 0][lr] = v.x; Bs[lc + 1][lr] = v.y;
            Bs[lc + 2][lr] = v.z; Bs[lc + 3][lr] = v.w;
        }
        __syncthreads();
        #pragma unroll
        for (int kk = 0; kk < 16; ++kk) {
            float av[4], bv[4];
            #pragma unroll
            for (int i = 0; i < 4; ++i) av[i] = As[kk][ty + 16 * i];
            #pragma unroll
            for (int j = 0; j < 4; ++j) bv[j] = Bs[kk][tx + 16 * j];
            #pragma unroll
            for (int i = 0; i < 4; ++i)
                #pragma unroll
                for (int j = 0; j < 4; ++j)
                    acc[i][j] = fmaf(av[i], bv[j], acc[i][j]);
        }
        __syncthreads();
    }

    float* pc = pbuf + (size_t)kz * MTOK * 96;
    #pragma unroll
    for (int i = 0; i < 4; ++i) {
        int m = m0 + ty + 16 * i;
        #pragma unroll
        for (int j = 0; j < 4; ++j) {
            int n = n0 + tx + 16 * j;
            if (n < 96) pc[(size_t)m * 96 + n] = acc[i][j];
        }
    }
}

__global__ __launch_bounds__(256) void reduce_xproj(const float* __restrict__ pbuf,
                                                    float* __restrict__ xdbl)
{
    const int idx = blockIdx.x * blockDim.x + threadIdx.x;
    const float4* p = reinterpret_cast<const float4*>(pbuf) + idx;
    float4 s = p[0];
    #pragma unroll
    for (int z = 1; z < XP_KS; ++z) {
        float4 v = p[(size_t)z * (MTOK * 96 / 4)];
        s.x += v.x; s.y += v.y; s.z += v.z; s.w += v.w;
    }
    reinterpret_cast<float4*>(xdbl)[idx] = s;
}

// causal depthwise conv (k=4, left pad 3) + bias + SiLU; bf16 in/out
__global__ __launch_bounds__(256) void conv_silu_kernel(const __bf16* __restrict__ xzb,
                                                        const float* __restrict__ cw,
                                                        const float* __restrict__ cb,
                                                        __bf16* __restrict__ xsb)
{
    int tid = blockIdx.x * blockDim.x + threadIdx.x;  // b*T*DINNER + t*DINNER + d
    int d = tid & (DINNER - 1);
    int t = (tid >> 11) & (T_LEN - 1);
    int b = tid >> 21;
    float acc = cb[d];
    const float4 w = *reinterpret_cast<const float4*>(&cw[d * DCONV]);
    float wv[4] = {w.x, w.y, w.z, w.w};
    #pragma unroll
    for (int j = 0; j < DCONV; ++j) {
        int tt = t - (DCONV - 1) + j;
        if (tt >= 0)
            acc = fmaf((float)xzb[((size_t)(b * T_LEN + tt)) * (2 * DINNER) + d], wv[j], acc);
    }
    xsb[tid] = (__bf16)(acc * sigmoid_f(acc));
}

// ---------------------------------------------------------------------------
// chunked selective scan, channel-per-thread, 16 states in registers.
// ---------------------------------------------------------------------------
__global__ __launch_bounds__(256) void scan_pass1(const __bf16* __restrict__ dtb,
                                                  const __bf16* __restrict__ xsb,
                                                  const float* __restrict__ xdbl,
                                                  const float* __restrict__ A_log,
                                                  float* __restrict__ Pb,
                                                  float* __restrict__ Bb)
{
    __shared__ float sB[CLEN][16];
    const int tid = threadIdx.x;
    const int g   = blockIdx.x * 256 + tid;     // global channel 0..4095
    const int c   = blockIdx.y;
    const int b   = g >> 11;
    const int d   = g & (DINNER - 1);
    const int m0  = b * T_LEN + c * CLEN;

    if (tid < CLEN * 4) {
        int t = tid >> 2, s4 = (tid & 3) * 4;
        *reinterpret_cast<float4*>(&sB[t][s4]) =
            *reinterpret_cast<const float4*>(&xdbl[(size_t)(m0 + t) * 96 + DTRANK + s4]);
    }
    __syncthreads();

    float a[DSTATE], h[DSTATE];
    #pragma unroll
    for (int s4 = 0; s4 < DSTATE; s4 += 4) {
        float4 v = *reinterpret_cast<const float4*>(&A_log[d * DSTATE + s4]);
        a[s4 + 0] = -__expf(v.x); a[s4 + 1] = -__expf(v.y);
        a[s4 + 2] = -__expf(v.z); a[s4 + 3] = -__expf(v.w);
        h[s4 + 0] = 0.f; h[s4 + 1] = 0.f; h[s4 + 2] = 0.f; h[s4 + 3] = 0.f;
    }

    float sumdt = 0.f;
    float dtc = (float)dtb[(size_t)m0 * DINNER + d];
    float xc  = (float)xsb[(size_t)m0 * DINNER + d];
    for (int t = 0; t < CLEN; ++t) {
        float dtn = 0.f, xn = 0.f;
        if (t + 1 < CLEN) {
            dtn = (float)dtb[(size_t)(m0 + t + 1) * DINNER + d];
            xn  = (float)xsb[(size_t)(m0 + t + 1) * DINNER + d];
        }
        sumdt += dtc;
        const float u = dtc * xc;
        #pragma unroll
        for (int s = 0; s < DSTATE; ++s) {
            const float dA = __expf(dtc * a[s]);
            h[s] = fmaf(dA, h[s], u * sB[t][s]);
        }
        dtc = dtn; xc = xn;
    }

    float* pp = Pb + ((size_t)c * NCH + g) * DSTATE;
    float* bp = Bb + ((size_t)c * NCH + g) * DSTATE;
    #pragma unroll
    for (int s4 = 0; s4 < DSTATE; s4 += 4) {
        float4 pv = {__expf(a[s4] * sumdt), __expf(a[s4 + 1] * sumdt),
                     __expf(a[s4 + 2] * sumdt), __expf(a[s4 + 3] * sumdt)};
        *reinterpret_cast<float4*>(pp + s4) = pv;
        float4 hv = {h[s4], h[s4 + 1], h[s4 + 2], h[s4 + 3]};
        *reinterpret_cast<float4*>(bp + s4) = hv;
    }
}

__global__ __launch_bounds__(256) void scan_pass2(const float* __restrict__ Pb,
                                                  float* __restrict__ Bb)
{
    const int idx = blockIdx.x * blockDim.x + threadIdx.x;  // 0..NSTATES-1
    float h = 0.f;
    #pragma unroll
    for (int c = 0; c < NC; ++c) {
        const size_t o = (size_t)c * NSTATES + idx;
        const float P  = Pb[o];
        const float Bv = Bb[o];
        Bb[o] = h;
        h = fmaf(P, h, Bv);
    }
}

__global__ __launch_bounds__(256) void scan_pass3(const __bf16* __restrict__ dtb,
                                                  const __bf16* __restrict__ xsb,
                                                  const float* __restrict__ xdbl,
                                                  const float* __restrict__ Hs,
                                                  const float* __restrict__ A_log,
                                                  const float* __restrict__ Dp,
                                                  const __bf16* __restrict__ xzb,
                                                  __bf16* __restrict__ yMb)
{
    __shared__ float sBC[CLEN][32];   // cols 0..15 = B, 16..31 = C
    const int tid = threadIdx.x;
    const int g   = blockIdx.x * 256 + tid;
    const int c   = blockIdx.y;
    const int b   = g >> 11;
    const int d   = g & (DINNER - 1);
    const int m0  = b * T_LEN + c * CLEN;

    {
        int t = tid >> 3, col = (tid & 7) * 4;
        if (t < CLEN)
            *reinterpret_cast<float4*>(&sBC[t][col]) =
                *reinterpret_cast<const float4*>(&xdbl[(size_t)(m0 + t) * 96 + DTRANK + col]);
    }
    __syncthreads();

    float a[DSTATE], h[DSTATE];
    #pragma unroll
    for (int s4 = 0; s4 < DSTATE; s4 += 4) {
        float4 v = *reinterpret_cast<const float4*>(&A_log[d * DSTATE + s4]);
        a[s4 + 0] = -__expf(v.x); a[s4 + 1] = -__expf(v.y);
        a[s4 + 2] = -__expf(v.z); a[s4 + 3] = -__expf(v.w);
        float4 hv = *reinterpret_cast<const float4*>(
            Hs + ((size_t)c * NCH + g) * DSTATE + s4);
        h[s4 + 0] = hv.x; h[s4 + 1] = hv.y; h[s4 + 2] = hv.z; h[s4 + 3] = hv.w;
    }
    const float Dv = Dp[d];

    float dtc = (float)dtb[(size_t)m0 * DINNER + d];
    float xc  = (float)xsb[(size_t)m0 * DINNER + d];
    float zc  = (float)xzb[(size_t)m0 * (2 * DINNER) + DINNER + d];
    for (int t = 0; t < CLEN; ++t) {
        float dtn = 0.f, xn = 0.f, zn = 0.f;
        if (t + 1 < CLEN) {
            dtn = (float)dtb[(size_t)(m0 + t + 1) * DINNER + d];
            xn  = (float)xsb[(size_t)(m0 + t + 1) * DINNER + d];
            zn  = (float)xzb[(size_t)(m0 + t + 1) * (2 * DINNER) + DINNER + d];
        }
        const float u = dtc * xc;
        float y0 = 0.f, y1 = 0.f, y2 = 0.f, y3 = 0.f;
        #pragma unroll
        for (int s = 0; s < DSTATE; s += 4) {
            float dA0 = __expf(dtc * a[s + 0]);
            float dA1 = __expf(dtc * a[s + 1]);
            float dA2 = __expf(dtc * a[s + 2]);
            float dA3 = __expf(dtc * a[s + 3]);
            h[s + 0] = fmaf(dA0, h[s + 0], u * sBC[t][s + 0]);
            h[s + 1] = fmaf(dA1, h[s + 1], u * sBC[t][s + 1]);
            h[s + 2] = fmaf(dA2, h[s + 2], u * sBC[t][s + 2]);
            h[s + 3] = fmaf(dA3, h[s + 3], u * sBC[t][s + 3]);
            y0 = fmaf(h[s + 0], sBC[t][16 + s + 0], y0);
            y1 = fmaf(h[s + 1], sBC[t][16 + s + 1], y1);
            y2 = fmaf(h[s + 2], sBC[t][16 + s + 2], y2);
            y3 = fmaf(h[s + 3], sBC[t][16 + s + 3], y3);
        }
        float y = (y0 + y1) + (y2 + y3) + xc * Dv;
        const float gate = zc * sigmoid_f(zc);
        yMb[(size_t)(m0 + t) * DINNER + d] = (__bf16)(y * gate);
        dtc = dtn; xc = xn; zc = zn;
    }
}

extern "C" void kernel_launch(void* const* d_in, const int* in_sizes, int n_in,
                              void* d_out, int out_size, void* d_ws, size_t ws_size,
                              hipStream_t stream) {
    const float* x         = (const float*)d_in[0];
    const float* in_proj_w = (const float*)d_in[1];
    const float* conv_w    = (const float*)d_in[2];
    const float* conv_b    = (const float*)d_in[3];
    const float* x_proj_w  = (const float*)d_in[4];
    const float* dt_proj_w = (const float*)d_in[5];
    const float* dt_proj_b = (const float*)d_in[6];
    const float* A_log     = (const float*)d_in[7];
    const float* D_param   = (const float*)d_in[8];
    const float* out_proj_w= (const float*)d_in[9];
    float* out = (float*)d_out;

    // ws layout (float units), no aliasing:
    // [0,4M)   xzb bf16 [2048][4096]
    // [4M,5M)  xb bf16      [5M,7M) wb_in bf16    [7M,8M) wb_out bf16
    // [8M,10M) xsb bf16     [10M,12M) dtb bf16
    // [12M,12.25M) xdbl fp32
    // [13M,16M) pbuf fp32
    // [16M,18M) Pb fp32     [18M,20M) Bb fp32
    // [20M,22M) yMb bf16
    float* ws = (float*)d_ws;
    const size_t M1 = (size_t)1024 * 1024;
    __bf16* xzb    = (__bf16*)ws;
    __bf16* xb     = (__bf16*)(ws + 4 * M1);
    __bf16* wb_in  = (__bf16*)(ws + 5 * M1);
    __bf16* wb_out = (__bf16*)(ws + 7 * M1);
    __bf16* xsb    = (__bf16*)(ws + 8 * M1);
    __bf16* dtb    = (__bf16*)(ws + 10 * M1);
    float*  xdbl   = ws + 12 * M1;
    float*  pbuf   = ws + 13 * M1;
    float*  Pb     = ws + 16 * M1;
    float*  Bb     = ws + 18 * M1;
    __bf16* yMb    = (__bf16*)(ws + 20 * M1);

    dim3 blk(256);

    // 0. bf16 conversions (x, in_proj_w, out_proj_w) in one dispatch
    convert3<<<dim3(4096), blk, 0, stream>>>(x, in_proj_w, out_proj_w, xb, wb_in, wb_out);

    // 1. in_proj (bf16 MFMA): xzb[m][4096] (bf16 out)
    mfma_gemm_bf16<128, __bf16><<<dim3((2 * DINNER) / 128, MTOK / 128), blk, 0, stream>>>(
        xb, DMODEL, wb_in, DMODEL, xzb, 2 * DINNER, DMODEL);

    // 2. causal conv + SiLU -> xsb[m][d] bf16
    conv_silu_kernel<<<dim3(B_SZ * T_LEN * DINNER / 256), blk, 0, stream>>>(xzb, conv_w, conv_b, xsb);

    // 3. x_proj split-K: pbuf[kz][m][96]
    gemm_xproj_splitk<<<dim3(2, MTOK / 64, XP_KS), blk, 0, stream>>>(xsb, x_proj_w, pbuf);

    // 4. reduce partials -> xdbl[m][96]
    reduce_xproj<<<dim3(MTOK * 96 / 4 / 256), blk, 0, stream>>>(pbuf, xdbl);

    // 5. dt_proj: dtb[m][i] = bf16(softplus(xdbl[:, :64] @ W^T + b[i]))
    gemm_dtproj<<<dim3(DINNER / 64, MTOK / 64), blk, 0, stream>>>(xdbl, dt_proj_w, dtb, dt_proj_b);

    // 6. chunked scan (fused gate+D epilogue in pass3) -> yMb bf16 [m][d]
    scan_pass1<<<dim3(NCH / 256, NC), blk, 0, stream>>>(dtb, xsb, xdbl, A_log, Pb, Bb);
    scan_pass2<<<dim3(NSTATES / 256), blk, 0, stream>>>(Pb, Bb);
    scan_pass3<<<dim3(NCH / 256, NC), blk, 0, stream>>>(dtb, xsb, xdbl, Bb, A_log, D_param, xzb, yMb);

    // 7. out_proj (bf16 MFMA): out[m][1024] = y @ out_proj_w^T (fp32 out)
    mfma_gemm_bf16<64, float><<<dim3(DMODEL / 64, MTOK / 128), blk, 0, stream>>>(
        yMb, DINNER, wb_out, DINNER, out, DMODEL, DINNER);
}